// Round 5
// baseline (451.158 us; speedup 1.0000x reference)
//
#include <hip/hip_runtime.h>
#include <hip/hip_bf16.h>
#include <math.h>
#include <type_traits>

#define AS1 __attribute__((address_space(1)))
#define AS3 __attribute__((address_space(3)))

typedef __bf16  bf16x8 __attribute__((ext_vector_type(8)));
typedef float   f32x4  __attribute__((ext_vector_type(4)));
typedef __hip_bfloat16 bf16;

#define MFMA16x16x32 __builtin_amdgcn_mfma_f32_16x16x32_bf16

__device__ __forceinline__ void gload16(const void* g, void* l) {
  // async global->LDS, 16B per lane; LDS dest = wave-uniform base + lane*16
  __builtin_amdgcn_global_load_lds((const AS1 void*)g, (AS3 void*)l, 16, 0, 0);
}

__device__ __forceinline__ unsigned short bfbits(float v) {
  return __builtin_bit_cast(unsigned short, __float2bfloat16(v));
}

#define LGKM0 __asm__ volatile("s_waitcnt lgkmcnt(0)" ::: "memory")
#define BARRIER __builtin_amdgcn_s_barrier()

// ---------------------------------------------------------------- fused fp32 -> bf16 casts
struct CastArgs {
  const float4* src[6];
  ushort4* dst[6];
  unsigned bound[6];  // cumulative float4 counts
};

__global__ __launch_bounds__(256) void f2bf_multi(CastArgs a) {
  unsigned i = blockIdx.x * 256 + threadIdx.x;
  if (i >= a.bound[5]) return;
  unsigned lo = 0;
  int s = 0;
#pragma unroll
  for (int k = 0; k < 5; k++) {
    if (i >= a.bound[k]) { s = k + 1; lo = a.bound[k]; }
  }
  unsigned idx = i - lo;
  float4 v = a.src[s][idx];
  ushort4 o;
  o.x = bfbits(v.x); o.y = bfbits(v.y); o.z = bfbits(v.z); o.w = bfbits(v.w);
  a.dst[s][idx] = o;
}

// ---------------------------------------------------------------- pipelined 256-wide GEMM
// C = A * W^T.  A: (M,K) bf16 row stride lda.  W: (N,K) bf16 contiguous (ldb=K).
// 512 threads = 8 waves (WGM x WGN).  K streamed as 32-wide sub-tiles through a
// ring of 4 LDS buffers; stage(s+3) issued before counted vmcnt(3L) -> loads for
// 3 sub-tiles always in flight (T3+T4).  Chunk-major LDS slot layout
// (slot = kchunk*ROWS + row) gives conflict-free ds_read_b128 (16 consecutive
// lanes -> 16 consecutive 16B slots); realized via pre-permuted global source
// addresses with a LINEAR global_load_lds dest (guide rule #21).  T5 setprio
// around the MFMA cluster.  KVUP variant: split K-half/V-transpose epilogue.
template <int BM, int BN, typename OutT, bool KVUP>
__global__ __launch_bounds__(512, 2) void gemm256(const bf16* __restrict__ A,
                                                  const bf16* __restrict__ W,
                                                  OutT* __restrict__ Cp,
                                                  bf16* __restrict__ vT,
                                                  int N, int K, int lda) {
  constexpr int WGN = (BN == 256) ? 4 : 2;
  constexpr int WGM = 8 / WGN;
  constexpr int MF = BM / WGM / 16;   // m-fragments per wave
  constexpr int NF = BN / WGN / 16;   // n-fragments per wave
  constexpr int LA = BM / 128;        // A gload16 per thread per sub-tile
  constexpr int LB = BN / 128;
  constexpr int L  = LA + LB;
  constexpr int ASUB = BM * 64;       // bytes per A sub-tile (BM x 32 bf16)
  constexpr int BSUB = BN * 64;
  __shared__ __align__(16) char lds[4 * (ASUB + BSUB)];
  char* ldsA = lds;
  char* ldsB = lds + 4 * ASUB;

  const int t = threadIdx.x, w = t >> 6, lane = t & 63;
  const int quad = lane >> 4, l16 = lane & 15;
  const int wm = w / WGN, wn = w % WGN;
  const int wrow = wm * (BM / WGM), wcol = wn * (BN / WGN);
  const size_t m0 = (size_t)blockIdx.x * BM;
  const size_t n0 = (size_t)blockIdx.y * BN;
  const int NT = K / 32;  // sub-tiles (all call sites: NT % 4 == 0, NT >= 8)

  // per-lane stage source bases (sub-tile-invariant).  slot = st*512 + w*64 + lane
  // maps to (row = slot % ROWS, kchunk = slot / ROWS): chunk-major LDS layout.
  const bf16* asrc[LA];
#pragma unroll
  for (int st = 0; st < LA; ++st) {
    int slot = st * 512 + w * 64 + lane;
    int row = slot % BM, chunk = slot / BM;
    asrc[st] = A + (m0 + row) * (size_t)lda + chunk * 8;
  }
  const bf16* bsrc[LB];
#pragma unroll
  for (int st = 0; st < LB; ++st) {
    int slot = st * 512 + w * 64 + lane;
    int row = slot % BN, chunk = slot / BN;
    bsrc[st] = W + (n0 + row) * (size_t)K + chunk * 8;
  }

  auto stage = [&](int s, int c) {
#pragma unroll
    for (int st = 0; st < LA; ++st)
      gload16(asrc[st] + s * 32, ldsA + c * ASUB + st * 8192 + w * 1024);
#pragma unroll
    for (int st = 0; st < LB; ++st)
      gload16(bsrc[st] + s * 32, ldsB + c * BSUB + st * 8192 + w * 1024);
  };

  f32x4 acc[MF][NF];
#pragma unroll
  for (int i = 0; i < MF; i++)
#pragma unroll
    for (int j = 0; j < NF; j++) acc[i][j] = f32x4{0.f, 0.f, 0.f, 0.f};

  auto compute = [&](int c) {
    bf16x8 af[MF], bw[NF];
#pragma unroll
    for (int nf = 0; nf < NF; ++nf)
      bw[nf] = *(const bf16x8*)(ldsB + c * BSUB +
                                (quad * BN + wcol + nf * 16 + l16) * 16);
#pragma unroll
    for (int mf = 0; mf < MF; ++mf)
      af[mf] = *(const bf16x8*)(ldsA + c * ASUB +
                                (quad * BM + wrow + mf * 16 + l16) * 16);
    __builtin_amdgcn_s_setprio(1);
#pragma unroll
    for (int mf = 0; mf < MF; ++mf)
#pragma unroll
      for (int nf = 0; nf < NF; ++nf)
        acc[mf][nf] = MFMA16x16x32(af[mf], bw[nf], acc[mf][nf], 0, 0, 0);
    __builtin_amdgcn_s_setprio(0);
  };

#define VM_STEADY do { if constexpr (L == 4) \
    __asm__ volatile("s_waitcnt vmcnt(12)" ::: "memory"); \
  else __asm__ volatile("s_waitcnt vmcnt(9)" ::: "memory"); } while (0)
#define VM_2 do { if constexpr (L == 4) \
    __asm__ volatile("s_waitcnt vmcnt(8)" ::: "memory"); \
  else __asm__ volatile("s_waitcnt vmcnt(6)" ::: "memory"); } while (0)
#define VM_1 do { if constexpr (L == 4) \
    __asm__ volatile("s_waitcnt vmcnt(4)" ::: "memory"); \
  else __asm__ volatile("s_waitcnt vmcnt(3)" ::: "memory"); } while (0)
#define VM_0 __asm__ volatile("s_waitcnt vmcnt(0)" ::: "memory")

  // prologue: 3 sub-tiles in flight
  stage(0, 0); stage(1, 1); stage(2, 2);

  // steady state: stage(s+3) -> wait own loads for s -> barrier -> compute(s&3)
  for (int s4 = 0; s4 < NT - 4; s4 += 4) {
#pragma unroll
    for (int jj = 0; jj < 4; ++jj) {
      stage(s4 + jj + 3, (jj + 3) & 3);
      VM_STEADY;
      BARRIER;
      compute(jj);
      LGKM0;
      BARRIER;
    }
  }
  // epilogue: last 4 sub-tiles (NT % 4 == 0 -> buffers 0..3)
  stage(NT - 1, 3);
  VM_STEADY; BARRIER; compute(0); LGKM0; BARRIER;
  VM_2;      BARRIER; compute(1); LGKM0; BARRIER;
  VM_1;      BARRIER; compute(2); LGKM0; BARRIER;
  VM_0;      BARRIER; compute(3);

#undef VM_STEADY
#undef VM_2
#undef VM_1
#undef VM_0

  if constexpr (!KVUP) {
#pragma unroll
    for (int mf = 0; mf < MF; ++mf)
#pragma unroll
      for (int nf = 0; nf < NF; ++nf)
#pragma unroll
        for (int r = 0; r < 4; ++r) {
          size_t row = m0 + wrow + mf * 16 + quad * 4 + r;
          size_t col = n0 + wcol + nf * 16 + l16;
          float v = acc[mf][nf][r];
          if constexpr (std::is_same<OutT, float>::value)
            Cp[row * N + col] = v;
          else
            Cp[row * N + col] = __float2bfloat16(v);
        }
  } else {
    // BM=BN=256: n-tile = one head (cols 0-127 = K-half, 128-255 = V-half)
    const int head = (int)(n0 >> 8);
    if (wcol < 128) {
      // K-half -> kvraw row-major (stride 4096)
#pragma unroll
      for (int mf = 0; mf < MF; ++mf)
#pragma unroll
        for (int nf = 0; nf < NF; ++nf)
#pragma unroll
          for (int r = 0; r < 4; ++r) {
            size_t row = m0 + wrow + mf * 16 + quad * 4 + r;
            size_t col = n0 + wcol + nf * 16 + l16;
            Cp[row * 4096 + col] = __float2bfloat16(acc[mf][nf][r]);
          }
    } else {
      // V-half -> vT[(b*16+h)*128 + d][t], 4 t-contiguous per store
#pragma unroll
      for (int mf = 0; mf < MF; ++mf) {
        size_t row = m0 + wrow + mf * 16 + quad * 4;  // +r all same b
        int bb = (int)(row >> 11), tloc = (int)(row & 2047);
#pragma unroll
        for (int nf = 0; nf < NF; ++nf) {
          int d = wcol - 128 + nf * 16 + l16;
          ushort4 v4;
          v4.x = bfbits(acc[mf][nf][0]);
          v4.y = bfbits(acc[mf][nf][1]);
          v4.z = bfbits(acc[mf][nf][2]);
          v4.w = bfbits(acc[mf][nf][3]);
          *(ushort4*)(vT + ((size_t)(bb * 16 + head) * 128 + d) * 2048 + tloc) = v4;
        }
      }
    }
  }
}

// ---------------------------------------------------------------- RoPE + RMSNorm
__global__ __launch_bounds__(256) void rope_rms(const bf16* __restrict__ qraw,
                                                const bf16* __restrict__ kvraw,
                                                const float* __restrict__ cosp,
                                                const float* __restrict__ sinp,
                                                bf16* __restrict__ qn,
                                                bf16* __restrict__ kn) {
  const int bt = blockIdx.x;
  const int w = threadIdx.x >> 6, lane = threadIdx.x & 63;
  const int h = blockIdx.y * 4 + w;
  const int tt = bt & 2047;  // T = 2048
  const float c = cosp[tt * 32 + (lane & 31)];
  const float s = sinp[tt * 32 + (lane & 31)];
  const float inv128 = 1.0f / 128.0f;
  const float eps = 1.1920929e-7f;

  // Q
  {
    const bf16* base = qraw + (size_t)bt * 2048 + h * 128;
    float a = (float)base[lane];
    float o = (float)base[64 + lane];
    float partner = __shfl_xor(o, 32);
    float orope = (lane < 32) ? (o * c + partner * s) : (o * c - partner * s);
    float ss = a * a + orope * orope;
#pragma unroll
    for (int off = 1; off < 64; off <<= 1) ss += __shfl_xor(ss, off);
    float rn = rsqrtf(ss * inv128 + eps);
    bf16* outp = qn + ((size_t)bt * 16 + h) * 128;
    outp[lane] = __float2bfloat16(a * rn);
    outp[64 + lane] = __float2bfloat16(orope * rn);
  }
  // K
  {
    const bf16* base = kvraw + (size_t)bt * 4096 + h * 256;
    float a = (float)base[lane];
    float o = (float)base[64 + lane];
    float partner = __shfl_xor(o, 32);
    float orope = (lane < 32) ? (o * c + partner * s) : (o * c - partner * s);
    float ss = a * a + orope * orope;
#pragma unroll
    for (int off = 1; off < 64; off <<= 1) ss += __shfl_xor(ss, off);
    float rn = rsqrtf(ss * inv128 + eps);
    bf16* outp = kn + ((size_t)bt * 16 + h) * 128;
    outp[lane] = __float2bfloat16(a * rn);
    outp[64 + lane] = __float2bfloat16(orope * rn);
  }
}

// ---------------------------------------------------------------- flash attention
// R3 version (best verified: 75.2 us): double-buffer K/V, prefetch + vmcnt(8),
// uniform pairing {31-pr, pr} = 33 tiles/block, KV loop unrolled x2 with
// compile-time buffer index, hoisted staging bases, setprio on MFMA clusters.
__global__ __launch_bounds__(256, 2) void attn_kernel(const bf16* __restrict__ qn,
                                                      const bf16* __restrict__ kn,
                                                      const bf16* __restrict__ vT,
                                                      bf16* __restrict__ y) {
  __shared__ __align__(16) bf16 Ks[2 * 64 * 128];   // [buf][s][d-chunks swizzled] 32 KB
  __shared__ __align__(16) bf16 Vs[2 * 128 * 64];   // [buf][d][s-chunks swizzled] 32 KB
  __shared__ __align__(16) bf16 Ps[4 * 16 * 64];    // per-wave P, swizzled         8 KB
  const int t = threadIdx.x, w = t >> 6, lane = t & 63;
  const int quad = lane >> 4, l16 = lane & 15;
  const int b = blockIdx.x >> 4, h = blockIdx.x & 15;
  const int pr = (int)blockIdx.y;  // 0..15
  const int T_ = 2048, H_ = 16;
  // p = exp2(sacc * K1 + K2) = e^(sacc/sqrt(128) - 12);  |q.k|/sqrt(128) <= sqrt(128) < 12
  const float K1 = 0.08838834764831845f * 1.4426950408889634f;
  const float K2 = -12.0f * 1.4426950408889634f;

  // per-lane tile-invariant staging bases
  const int cgk = l16 ^ ((w * 4 + quad) & 7);
  const char* kg0 = (const char*)(kn + ((size_t)(b * T_) * H_ + h) * 128)
                    + (size_t)(w * 4 + quad) * 4096 + (size_t)cgk * 16;
  const int vrow = w * 8 + (lane >> 3);
  const int cgv = (lane & 7) ^ (vrow & 7);
  const char* vg0 = (const char*)(vT + ((size_t)(b * H_ + h) * 128 + vrow) * T_)
                    + (size_t)cgv * 16;

  // stage K/V tile it2 into LDS buffer BUF (compile-time)
  auto stage = [&](auto bufc, int it2) {
    constexpr int BUF = decltype(bufc)::value;
    const size_t koff = (size_t)it2 * 262144;  // 64 rows * 4096 B
    const size_t voff = (size_t)it2 * 128;     // 64 cols * 2 B
#pragma unroll
    for (int is = 0; is < 4; ++is)
      gload16(kg0 + koff + (size_t)is * 65536,
              (char*)Ks + BUF * 16384 + is * 4096 + w * 1024);
#pragma unroll
    for (int is = 0; is < 4; ++is)
      gload16(vg0 + voff + (size_t)is * 131072,
              (char*)Vs + BUF * 16384 + is * 4096 + w * 1024);
  };

  // one KV tile: prefetch next into 1-BUF, sync, QK^T, softmax, P->LDS, PV
  auto body = [&](auto bufc, int it, int nt, int xb,
                  bf16x8* qf, f32x4* yacc, float* lrow) {
    constexpr int BUF = decltype(bufc)::value;
    if (it + 1 < nt) {
      stage(std::integral_constant<int, 1 - BUF>{}, it + 1);
      __asm__ volatile("s_waitcnt vmcnt(8)" ::: "memory");  // tile-it loads done
    } else {
      __asm__ volatile("s_waitcnt vmcnt(0)" ::: "memory");
    }
    __asm__ volatile("s_barrier" ::: "memory");

    // S = Q K^T   (kf addr: BUF/cg in offset-immediate, one vaddr per ks)
    f32x4 sacc[4];
#pragma unroll
    for (int cg = 0; cg < 4; cg++) sacc[cg] = f32x4{0.f, 0.f, 0.f, 0.f};
    __builtin_amdgcn_s_setprio(1);
#pragma unroll
    for (int cg = 0; cg < 4; ++cg) {
#pragma unroll
      for (int ks = 0; ks < 4; ++ks) {
        const int pos = (ks * 4 + quad) ^ (l16 & 7);  // srow&7 == l16&7
        const bf16x8 kf = *(const bf16x8*)((const char*)Ks + BUF * 16384 +
                                           (cg * 16 + l16) * 256 + pos * 16);
        sacc[cg] = MFMA16x16x32(qf[ks], kf, sacc[cg], 0, 0, 0);
      }
    }
    __builtin_amdgcn_s_setprio(0);

    // fixed-max softmax: p = exp2(s*K1 + K2); per-lane partial l
    const bool diag = (it == xb);
    float p[4][4];
#pragma unroll
    for (int cg = 0; cg < 4; ++cg)
#pragma unroll
      for (int r = 0; r < 4; ++r) {
        float e;
        if (diag && (cg * 16 + l16 > w * 16 + quad * 4 + r))
          e = 0.0f;
        else
          e = exp2f(fmaf(sacc[cg][r], K1, K2));
        p[cg][r] = e;
        lrow[r] += e;
      }

    // P: C-layout -> LDS (stride 64, chunk-XOR swizzle) -> A-layout
#pragma unroll
    for (int cg = 0; cg < 4; cg++)
#pragma unroll
      for (int r = 0; r < 4; r++) {
        const int row = quad * 4 + r;
        const int col = cg * 16 + l16;
        Ps[w * 1024 + row * 64 + (((col >> 3) ^ (row & 7)) << 3) + (col & 7)] =
            __float2bfloat16(p[cg][r]);
      }
    __asm__ volatile("s_waitcnt lgkmcnt(0)" ::: "memory");

    bf16x8 pf[2];
#pragma unroll
    for (int k2 = 0; k2 < 2; k2++)
      pf[k2] = *(const bf16x8*)(&Ps[w * 1024 + l16 * 64 +
                                    (((k2 * 4 + quad) ^ (l16 & 7)) << 3)]);
    __builtin_amdgcn_s_setprio(1);
#pragma unroll
    for (int dg = 0; dg < 8; dg++) {
#pragma unroll
      for (int k2 = 0; k2 < 2; k2++) {
        const int pos = (k2 * 4 + quad) ^ (l16 & 7);  // drow&7 == l16&7
        const bf16x8 vf = *(const bf16x8*)((const char*)Vs + BUF * 16384 +
                                           (dg * 16 + l16) * 128 + pos * 16);
        yacc[dg] = MFMA16x16x32(pf[k2], vf, yacc[dg], 0, 0, 0);
      }
    }
    __builtin_amdgcn_s_setprio(0);
    __asm__ volatile("s_barrier" ::: "memory");  // 1-BUF free to overwrite
  };

  const std::integral_constant<int, 0> c0{};
  const std::integral_constant<int, 1> c1{};

  for (int sidx = 0; sidx < 2; ++sidx) {
    const int xb = sidx ? pr : (31 - pr);  // long strip first, then short
    const int q0 = xb * 64;
    const int nt = xb + 1;

    bf16x8 qf[4];
    {
      const bf16* qbase = qn + ((size_t)(b * T_ + q0 + w * 16 + l16) * H_ + h) * 128;
#pragma unroll
      for (int ks = 0; ks < 4; ks++) qf[ks] = *(const bf16x8*)(qbase + ks * 32 + quad * 8);
    }
    f32x4 yacc[8];
#pragma unroll
    for (int i = 0; i < 8; i++) yacc[i] = f32x4{0.f, 0.f, 0.f, 0.f};
    float lrow[4] = {0.f, 0.f, 0.f, 0.f};

    stage(c0, 0);  // prologue prefetch into buf0
    int it = 0;
    for (; it + 2 <= nt; it += 2) {
      body(c0, it, nt, xb, qf, yacc, lrow);
      body(c1, it + 1, nt, xb, qf, yacc, lrow);
    }
    if (it < nt) body(c0, it, nt, xb, qf, yacc, lrow);  // odd tail uses buf0

    // epilogue: reduce per-lane l partials across the 16 cols once, then scale
#pragma unroll
    for (int off = 1; off < 16; off <<= 1)
#pragma unroll
      for (int r = 0; r < 4; r++) lrow[r] += __shfl_xor(lrow[r], off);
#pragma unroll
    for (int r = 0; r < 4; r++) {
      float inv = 1.0f / lrow[r];
      size_t qrow = (size_t)(b * T_ + q0 + w * 16 + quad * 4 + r);
      bf16* outp = y + qrow * 2048 + h * 128;
#pragma unroll
      for (int dg = 0; dg < 8; dg++)
        outp[dg * 16 + l16] = __float2bfloat16(yacc[dg][r] * inv);
    }
  }
}

// ---------------------------------------------------------------- launcher
extern "C" void kernel_launch(void* const* d_in, const int* in_sizes, int n_in,
                              void* d_out, int out_size, void* d_ws, size_t ws_size,
                              hipStream_t stream) {
  (void)in_sizes; (void)n_in; (void)out_size; (void)ws_size;
  const float* x    = (const float*)d_in[0];
  const float* cosp = (const float*)d_in[1];
  const float* sinp = (const float*)d_in[2];
  const float* wqd  = (const float*)d_in[3];
  const float* wqu  = (const float*)d_in[4];
  const float* wkvd = (const float*)d_in[5];
  const float* wkvu = (const float*)d_in[6];
  const float* wo   = (const float*)d_in[7];
  float* out = (float*)d_out;

  char* ws = (char*)d_ws;
  size_t off = 0;
  auto alloc = [&](size_t elems) { bf16* p = (bf16*)(ws + off); off += elems * 2; return p; };
  bf16* xb      = alloc((size_t)4096 * 2048);
  bf16* wqdB    = alloc((size_t)1536 * 2048);  // wqdB+wkvdB contiguous: fused (2048,2048) W
  bf16* wkvdB   = alloc((size_t)512 * 2048);
  bf16* wquB    = alloc((size_t)2048 * 1536);
  bf16* wkvuB   = alloc((size_t)4096 * 512);
  bf16* woB     = alloc((size_t)2048 * 2048);
  bf16* qkvdown = alloc((size_t)4096 * 2048);  // cols 0..1535 = qdown, 1536..2047 = kvdown
  bf16* qraw    = alloc((size_t)4096 * 2048);
  bf16* kvraw   = alloc((size_t)4096 * 4096);  // only K-halves written/used
  bf16* qnb     = alloc((size_t)4096 * 16 * 128);
  bf16* knb     = alloc((size_t)4096 * 16 * 128);
  bf16* vTb     = alloc((size_t)2 * 16 * 128 * 2048);
  bf16* yb      = alloc((size_t)4096 * 2048);

  // one fused cast launch for all six fp32->bf16 conversions
  CastArgs ca;
  const float* srcs[6] = {x, wqd, wkvd, wqu, wkvu, wo};
  bf16* dsts[6]        = {xb, wqdB, wkvdB, wquB, wkvuB, woB};
  size_t cnts[6] = {(size_t)4096 * 2048, (size_t)1536 * 2048, (size_t)512 * 2048,
                    (size_t)2048 * 1536, (size_t)4096 * 512,  (size_t)2048 * 2048};
  unsigned cum = 0;
  for (int i = 0; i < 6; i++) {
    ca.src[i] = (const float4*)srcs[i];
    ca.dst[i] = (ushort4*)dsts[i];
    cum += (unsigned)(cnts[i] / 4);
    ca.bound[i] = cum;
  }
  f2bf_multi<<<dim3((cum + 255) / 256), 256, 0, stream>>>(ca);

  // fused down-proj: (4096 x 2048) = x @ [wq_down; wkv_down]^T
  gemm256<256, 128, bf16, false><<<dim3(16, 16), 512, 0, stream>>>(
      xb, wqdB, qkvdown, nullptr, 2048, 2048, 2048);
  // q up-projection (strided A)
  gemm256<256, 128, bf16, false><<<dim3(16, 16), 512, 0, stream>>>(
      qkvdown, wquB, qraw, nullptr, 2048, 1536, 2048);
  // kv up-projection with fused K-half / V-transpose epilogue
  gemm256<256, 256, bf16, true><<<dim3(16, 16), 512, 0, stream>>>(
      qkvdown + 1536, wkvuB, kvraw, vTb, 4096, 512, 2048);
  rope_rms<<<dim3(4096, 4), 256, 0, stream>>>(qraw, kvraw, cosp, sinp, qnb, knb);
  attn_kernel<<<dim3(32, 16), 256, 0, stream>>>(qnb, knb, vTb, yb);
  gemm256<256, 128, float, false><<<dim3(16, 16), 512, 0, stream>>>(
      yb, woB, out, nullptr, 2048, 2048, 2048);
}

// Round 7
// 400.225 us; speedup vs baseline: 1.1273x; 1.1273x over previous
//
#include <hip/hip_runtime.h>
#include <hip/hip_bf16.h>
#include <math.h>
#include <type_traits>

#define AS1 __attribute__((address_space(1)))
#define AS3 __attribute__((address_space(3)))

typedef __bf16  bf16x8 __attribute__((ext_vector_type(8)));
typedef float   f32x4  __attribute__((ext_vector_type(4)));
typedef __hip_bfloat16 bf16;

#define MFMA16x16x32 __builtin_amdgcn_mfma_f32_16x16x32_bf16

__device__ __forceinline__ void gload16(const void* g, void* l) {
  // async global->LDS, 16B per lane; LDS dest = wave-uniform base + lane*16
  __builtin_amdgcn_global_load_lds((const AS1 void*)g, (AS3 void*)l, 16, 0, 0);
}

__device__ __forceinline__ unsigned short bfbits(float v) {
  return __builtin_bit_cast(unsigned short, __float2bfloat16(v));
}

#define LGKM0 __asm__ volatile("s_waitcnt lgkmcnt(0)" ::: "memory")
#define BARRIER __builtin_amdgcn_s_barrier()
#define VMCNT(n) __asm__ volatile("s_waitcnt vmcnt(" #n ")" ::: "memory")

// ---------------------------------------------------------------- fused fp32 -> bf16 casts
struct CastArgs {
  const float4* src[6];
  ushort4* dst[6];
  unsigned bound[6];  // cumulative float4 counts
};

__global__ __launch_bounds__(256) void f2bf_multi(CastArgs a) {
  unsigned i = blockIdx.x * 256 + threadIdx.x;
  if (i >= a.bound[5]) return;
  unsigned lo = 0;
  int s = 0;
#pragma unroll
  for (int k = 0; k < 5; k++) {
    if (i >= a.bound[k]) { s = k + 1; lo = a.bound[k]; }
  }
  unsigned idx = i - lo;
  float4 v = a.src[s][idx];
  ushort4 o;
  o.x = bfbits(v.x); o.y = bfbits(v.y); o.z = bfbits(v.z); o.w = bfbits(v.w);
  a.dst[s][idx] = o;
}

// ---------------------------------------------------------------- 256x256 8-phase GEMM
// C = A*W^T.  A:(M,K) bf16 stride lda.  W:(N,K) bf16 (ldb=K).  8 waves (2Mx4N),
// BK=64, 2 K-tiles per iteration, 8 phases x 16 MFMA.  LDS 128 KiB: A[2 slots]
// [2 halves][64 rows][64 cols] + B same; slot = kt&1.  T2: chunk^(row&7) LDS
// swizzle realized by pre-swizzled global sources (linear gload_lds dest).
// T4: vmcnt(2) at P2-end / P6-end only (counted, never 0 mid-loop); safety rule:
// reads of a K-tile occur only after a barrier preceded in EVERY wave by a vmcnt
// covering that tile's staging loads.  T5: setprio around each MFMA cluster.
template <typename OutT, bool KVUP>
__global__ __launch_bounds__(512, 2) void gemm8p(const bf16* __restrict__ A,
                                                 const bf16* __restrict__ W,
                                                 OutT* __restrict__ Cp,
                                                 bf16* __restrict__ vT,
                                                 int N, int K, int lda) {
  __shared__ __align__(16) char lds[131072];
  const int t = threadIdx.x, w = t >> 6, lane = t & 63;
  const int quad = lane >> 4, l16 = lane & 15;
  const int wr = w >> 2, wc = w & 3;  // 2x4 wave grid; wave tile 128x64
  const size_t m0 = (size_t)blockIdx.x * 256;
  const size_t n0 = (size_t)blockIdx.y * 256;
  const int NI = K >> 7;  // iterations (2 K-tiles each); all call sites NI>=4

  // staging bases: thread covers (row = h*128 + s*64 + w*8 + lane>>3,
  // chunk = lane&7), source chunk pre-swizzled by ^(row&7) = ^(lane>>3 & 7)
  const int srow = w * 8 + (lane >> 3);
  const int schunk = (lane & 7) ^ ((lane >> 3) & 7);
  const bf16* aS = A + (m0 + srow) * (size_t)lda + schunk * 8;
  const bf16* bS = W + (n0 + srow) * (size_t)K + schunk * 8;

  auto stageA = [&](int kt, int h) {
    const bf16* src = aS + (size_t)(h * 128) * lda + kt * 64;
    char* dst = lds + (kt & 1) * 32768 + h * 16384 + w * 1024;
    gload16(src, dst);                          // sweep 0 (rows +0..63)
    gload16(src + (size_t)64 * lda, dst + 8192);// sweep 1 (rows +64..127)
  };
  auto stageB = [&](int kt, int h) {
    const bf16* src = bS + (size_t)(h * 128) * K + kt * 64;
    char* dst = lds + 65536 + (kt & 1) * 32768 + h * 16384 + w * 1024;
    gload16(src, dst);
    gload16(src + (size_t)64 * K, dst + 8192);
  };

  // per-lane read bases; chunk = (kh*4+quad)^(l16&7) (row&7 == l16&7)
  const int cq0 = ((quad) ^ (l16 & 7)) * 16;
  const int cq1 = ((4 + quad) ^ (l16 & 7)) * 16;
  const char* aRb = lds + wr * 16384 + l16 * 128;
  const char* bRb = lds + 65536 + (wc >> 1) * 16384 + ((wc & 1) * 64 + l16) * 128;
  auto rdA = [&](int sl, int mf, int kh) -> bf16x8 {
    return *(const bf16x8*)(aRb + sl * 32768 + mf * 2048 + (kh ? cq1 : cq0));
  };
  auto rdB = [&](int sl, int nf, int kh) -> bf16x8 {
    return *(const bf16x8*)(bRb + sl * 32768 + nf * 2048 + (kh ? cq1 : cq0));
  };

  bf16x8 aR[8][2], bR[4][2];
  f32x4 acc[8][4];
#pragma unroll
  for (int i = 0; i < 8; i++)
#pragma unroll
    for (int j = 0; j < 4; j++) acc[i][j] = f32x4{0.f, 0.f, 0.f, 0.f};

  auto cluster = [&](int mh, int nh) {  // 4mf x 2nf x 2kh = 16 MFMA
    __builtin_amdgcn_s_setprio(1);
#pragma unroll
    for (int m2 = 0; m2 < 4; ++m2)
#pragma unroll
      for (int n2 = 0; n2 < 2; ++n2)
#pragma unroll
        for (int kh = 0; kh < 2; ++kh)
          acc[mh * 4 + m2][nh * 2 + n2] =
              MFMA16x16x32(aR[mh * 4 + m2][kh], bR[nh * 2 + n2][kh],
                           acc[mh * 4 + m2][nh * 2 + n2], 0, 0, 0);
    __builtin_amdgcn_s_setprio(0);
  };

  // ---- prologue: stage kt0 + kt1 fully (16 loads), wait kt0, preload c0 frags
  stageA(0, 0); stageA(0, 1); stageB(0, 0); stageB(0, 1);
  stageA(1, 0); stageA(1, 1); stageB(1, 0); stageB(1, 1);
  VMCNT(8);
  BARRIER;
#pragma unroll
  for (int mf = 0; mf < 4; ++mf)
#pragma unroll
    for (int kh = 0; kh < 2; ++kh) aR[mf][kh] = rdA(0, mf, kh);
#pragma unroll
  for (int nf = 0; nf < 2; ++nf)
#pragma unroll
    for (int kh = 0; kh < 2; ++kh) bR[nf][kh] = rdB(0, nf, kh);

  for (int i = 0; i < NI; ++i) {
    const int kt1 = 2 * i + 1, kt2 = 2 * i + 2, kt3 = 2 * i + 3;
    const bool hn = (i + 1 < NI);

    // P0: rd kt0.b23 | stage kt1.B0 | c(0,0)
#pragma unroll
    for (int kh = 0; kh < 2; ++kh) { bR[2][kh] = rdB(0, 2, kh); bR[3][kh] = rdB(0, 3, kh); }
    if (i > 0) stageB(kt1, 0);
    BARRIER; LGKM0;
    cluster(0, 0);
    BARRIER;

    // P1: rd kt0.a47 | stage kt1.B1 | c(0,1)
#pragma unroll
    for (int mf = 0; mf < 4; ++mf)
#pragma unroll
      for (int kh = 0; kh < 2; ++kh) aR[4 + mf][kh] = rdA(0, 4 + mf, kh);
    if (i > 0) stageB(kt1, 1);
    BARRIER; LGKM0;
    cluster(0, 1);
    BARRIER;

    // P2: stage kt2.A0 | c(1,0) | vmcnt covering kt1 before P3's reads
    if (hn) stageA(kt2, 0);
    BARRIER; LGKM0;
    cluster(1, 0);
    if (hn) { VMCNT(2); } else { VMCNT(0); }
    BARRIER;

    // P3: rd kt1.a03 + kt1.b01 | stage kt2.A1 | c(1,1)
#pragma unroll
    for (int mf = 0; mf < 4; ++mf)
#pragma unroll
      for (int kh = 0; kh < 2; ++kh) aR[mf][kh] = rdA(1, mf, kh);
#pragma unroll
    for (int nf = 0; nf < 2; ++nf)
#pragma unroll
      for (int kh = 0; kh < 2; ++kh) bR[nf][kh] = rdB(1, nf, kh);
    if (hn) stageA(kt2, 1);
    BARRIER; LGKM0;
    cluster(1, 1);
    BARRIER;

    // P4: rd kt1.b23 | stage kt2.B0 | c(0,0)
#pragma unroll
    for (int kh = 0; kh < 2; ++kh) { bR[2][kh] = rdB(1, 2, kh); bR[3][kh] = rdB(1, 3, kh); }
    if (hn) stageB(kt2, 0);
    BARRIER; LGKM0;
    cluster(0, 0);
    BARRIER;

    // P5: rd kt1.a47 | stage kt2.B1 | c(0,1)
#pragma unroll
    for (int mf = 0; mf < 4; ++mf)
#pragma unroll
      for (int kh = 0; kh < 2; ++kh) aR[4 + mf][kh] = rdA(1, 4 + mf, kh);
    if (hn) stageB(kt2, 1);
    BARRIER; LGKM0;
    cluster(0, 1);
    BARRIER;

    // P6: stage kt3.A0 | c(1,0) | vmcnt covering kt2 before P7's reads
    if (hn) stageA(kt3, 0);
    BARRIER; LGKM0;
    cluster(1, 0);
    if (hn) { VMCNT(2); }
    BARRIER;

    // P7: rd kt2.a03 + kt2.b01 | stage kt3.A1 | c(1,1)
    if (hn) {
#pragma unroll
      for (int mf = 0; mf < 4; ++mf)
#pragma unroll
        for (int kh = 0; kh < 2; ++kh) aR[mf][kh] = rdA(0, mf, kh);
#pragma unroll
      for (int nf = 0; nf < 2; ++nf)
#pragma unroll
        for (int kh = 0; kh < 2; ++kh) bR[nf][kh] = rdB(0, nf, kh);
      stageA(kt3, 1);
    }
    BARRIER; LGKM0;
    cluster(1, 1);
    BARRIER;
  }

  // ---- epilogue
  if constexpr (!KVUP) {
#pragma unroll
    for (int mf = 0; mf < 8; ++mf)
#pragma unroll
      for (int nf = 0; nf < 4; ++nf)
#pragma unroll
        for (int r = 0; r < 4; ++r) {
          size_t row = m0 + wr * 128 + mf * 16 + quad * 4 + r;
          size_t col = n0 + wc * 64 + nf * 16 + l16;
          float v = acc[mf][nf][r];
          if constexpr (std::is_same<OutT, float>::value)
            Cp[row * N + col] = v;
          else
            Cp[row * N + col] = __float2bfloat16(v);
        }
  } else {
    // n-tile 256 = one head; wc 0,1 -> K-half (cols 0-127); wc 2,3 -> V-half
    const int head = (int)(n0 >> 8);
    if (wc < 2) {
#pragma unroll
      for (int mf = 0; mf < 8; ++mf)
#pragma unroll
        for (int nf = 0; nf < 4; ++nf)
#pragma unroll
          for (int r = 0; r < 4; ++r) {
            size_t row = m0 + wr * 128 + mf * 16 + quad * 4 + r;
            size_t col = n0 + wc * 64 + nf * 16 + l16;
            Cp[row * 4096 + col] = __float2bfloat16(acc[mf][nf][r]);
          }
    } else {
#pragma unroll
      for (int mf = 0; mf < 8; ++mf) {
        size_t row = m0 + wr * 128 + mf * 16 + quad * 4;  // +r all same b-block
        int bb = (int)(row >> 11), tloc = (int)(row & 2047);
#pragma unroll
        for (int nf = 0; nf < 4; ++nf) {
          int d = (wc - 2) * 64 + nf * 16 + l16;
          ushort4 v4;
          v4.x = bfbits(acc[mf][nf][0]);
          v4.y = bfbits(acc[mf][nf][1]);
          v4.z = bfbits(acc[mf][nf][2]);
          v4.w = bfbits(acc[mf][nf][3]);
          *(ushort4*)(vT + ((size_t)(bb * 16 + head) * 128 + d) * 2048 + tloc) = v4;
        }
      }
    }
  }
}

// ---------------------------------------------------------------- RoPE + RMSNorm
__global__ __launch_bounds__(256) void rope_rms(const bf16* __restrict__ qraw,
                                                const bf16* __restrict__ kvraw,
                                                const float* __restrict__ cosp,
                                                const float* __restrict__ sinp,
                                                bf16* __restrict__ qn,
                                                bf16* __restrict__ kn) {
  const int bt = blockIdx.x;
  const int w = threadIdx.x >> 6, lane = threadIdx.x & 63;
  const int h = blockIdx.y * 4 + w;
  const int tt = bt & 2047;  // T = 2048
  const float c = cosp[tt * 32 + (lane & 31)];
  const float s = sinp[tt * 32 + (lane & 31)];
  const float inv128 = 1.0f / 128.0f;
  const float eps = 1.1920929e-7f;

  // Q
  {
    const bf16* base = qraw + (size_t)bt * 2048 + h * 128;
    float a = (float)base[lane];
    float o = (float)base[64 + lane];
    float partner = __shfl_xor(o, 32);
    float orope = (lane < 32) ? (o * c + partner * s) : (o * c - partner * s);
    float ss = a * a + orope * orope;
#pragma unroll
    for (int off = 1; off < 64; off <<= 1) ss += __shfl_xor(ss, off);
    float rn = rsqrtf(ss * inv128 + eps);
    bf16* outp = qn + ((size_t)bt * 16 + h) * 128;
    outp[lane] = __float2bfloat16(a * rn);
    outp[64 + lane] = __float2bfloat16(orope * rn);
  }
  // K
  {
    const bf16* base = kvraw + (size_t)bt * 4096 + h * 256;
    float a = (float)base[lane];
    float o = (float)base[64 + lane];
    float partner = __shfl_xor(o, 32);
    float orope = (lane < 32) ? (o * c + partner * s) : (o * c - partner * s);
    float ss = a * a + orope * orope;
#pragma unroll
    for (int off = 1; off < 64; off <<= 1) ss += __shfl_xor(ss, off);
    float rn = rsqrtf(ss * inv128 + eps);
    bf16* outp = kn + ((size_t)bt * 16 + h) * 128;
    outp[lane] = __float2bfloat16(a * rn);
    outp[64 + lane] = __float2bfloat16(orope * rn);
  }
}

// ---------------------------------------------------------------- flash attention
// R3 version (best verified: 75.2 us): double-buffer K/V, prefetch + vmcnt(8),
// uniform pairing {31-pr, pr} = 33 tiles/block, KV loop unrolled x2 with
// compile-time buffer index, hoisted staging bases, setprio on MFMA clusters.
__global__ __launch_bounds__(256, 2) void attn_kernel(const bf16* __restrict__ qn,
                                                      const bf16* __restrict__ kn,
                                                      const bf16* __restrict__ vT,
                                                      bf16* __restrict__ y) {
  __shared__ __align__(16) bf16 Ks[2 * 64 * 128];   // [buf][s][d-chunks swizzled] 32 KB
  __shared__ __align__(16) bf16 Vs[2 * 128 * 64];   // [buf][d][s-chunks swizzled] 32 KB
  __shared__ __align__(16) bf16 Ps[4 * 16 * 64];    // per-wave P, swizzled         8 KB
  const int t = threadIdx.x, w = t >> 6, lane = t & 63;
  const int quad = lane >> 4, l16 = lane & 15;
  const int b = blockIdx.x >> 4, h = blockIdx.x & 15;
  const int pr = (int)blockIdx.y;  // 0..15
  const int T_ = 2048, H_ = 16;
  // p = exp2(sacc * K1 + K2) = e^(sacc/sqrt(128) - 12);  |q.k|/sqrt(128) <= sqrt(128) < 12
  const float K1 = 0.08838834764831845f * 1.4426950408889634f;
  const float K2 = -12.0f * 1.4426950408889634f;

  // per-lane tile-invariant staging bases
  const int cgk = l16 ^ ((w * 4 + quad) & 7);
  const char* kg0 = (const char*)(kn + ((size_t)(b * T_) * H_ + h) * 128)
                    + (size_t)(w * 4 + quad) * 4096 + (size_t)cgk * 16;
  const int vrow = w * 8 + (lane >> 3);
  const int cgv = (lane & 7) ^ (vrow & 7);
  const char* vg0 = (const char*)(vT + ((size_t)(b * H_ + h) * 128 + vrow) * T_)
                    + (size_t)cgv * 16;

  // stage K/V tile it2 into LDS buffer BUF (compile-time)
  auto stage = [&](auto bufc, int it2) {
    constexpr int BUF = decltype(bufc)::value;
    const size_t koff = (size_t)it2 * 262144;  // 64 rows * 4096 B
    const size_t voff = (size_t)it2 * 128;     // 64 cols * 2 B
#pragma unroll
    for (int is = 0; is < 4; ++is)
      gload16(kg0 + koff + (size_t)is * 65536,
              (char*)Ks + BUF * 16384 + is * 4096 + w * 1024);
#pragma unroll
    for (int is = 0; is < 4; ++is)
      gload16(vg0 + voff + (size_t)is * 131072,
              (char*)Vs + BUF * 16384 + is * 4096 + w * 1024);
  };

  // one KV tile: prefetch next into 1-BUF, sync, QK^T, softmax, P->LDS, PV
  auto body = [&](auto bufc, int it, int nt, int xb,
                  bf16x8* qf, f32x4* yacc, float* lrow) {
    constexpr int BUF = decltype(bufc)::value;
    if (it + 1 < nt) {
      stage(std::integral_constant<int, 1 - BUF>{}, it + 1);
      __asm__ volatile("s_waitcnt vmcnt(8)" ::: "memory");  // tile-it loads done
    } else {
      __asm__ volatile("s_waitcnt vmcnt(0)" ::: "memory");
    }
    __asm__ volatile("s_barrier" ::: "memory");

    // S = Q K^T   (kf addr: BUF/cg in offset-immediate, one vaddr per ks)
    f32x4 sacc[4];
#pragma unroll
    for (int cg = 0; cg < 4; cg++) sacc[cg] = f32x4{0.f, 0.f, 0.f, 0.f};
    __builtin_amdgcn_s_setprio(1);
#pragma unroll
    for (int cg = 0; cg < 4; ++cg) {
#pragma unroll
      for (int ks = 0; ks < 4; ++ks) {
        const int pos = (ks * 4 + quad) ^ (l16 & 7);  // srow&7 == l16&7
        const bf16x8 kf = *(const bf16x8*)((const char*)Ks + BUF * 16384 +
                                           (cg * 16 + l16) * 256 + pos * 16);
        sacc[cg] = MFMA16x16x32(qf[ks], kf, sacc[cg], 0, 0, 0);
      }
    }
    __builtin_amdgcn_s_setprio(0);

    // fixed-max softmax: p = exp2(s*K1 + K2); per-lane partial l
    const bool diag = (it == xb);
    float p[4][4];
#pragma unroll
    for (int cg = 0; cg < 4; ++cg)
#pragma unroll
      for (int r = 0; r < 4; ++r) {
        float e;
        if (diag && (cg * 16 + l16 > w * 16 + quad * 4 + r))
          e = 0.0f;
        else
          e = exp2f(fmaf(sacc[cg][r], K1, K2));
        p[cg][r] = e;
        lrow[r] += e;
      }

    // P: C-layout -> LDS (stride 64, chunk-XOR swizzle) -> A-layout
#pragma unroll
    for (int cg = 0; cg < 4; cg++)
#pragma unroll
      for (int r = 0; r < 4; r++) {
        const int row = quad * 4 + r;
        const int col = cg * 16 + l16;
        Ps[w * 1024 + row * 64 + (((col >> 3) ^ (row & 7)) << 3) + (col & 7)] =
            __float2bfloat16(p[cg][r]);
      }
    __asm__ volatile("s_waitcnt lgkmcnt(0)" ::: "memory");

    bf16x8 pf[2];
#pragma unroll
    for (int k2 = 0; k2 < 2; k2++)
      pf[k2] = *(const bf16x8*)(&Ps[w * 1024 + l16 * 64 +
                                    (((k2 * 4 + quad) ^ (l16 & 7)) << 3)]);
    __builtin_amdgcn_s_setprio(1);
#pragma unroll
    for (int dg = 0; dg < 8; dg++) {
#pragma unroll
      for (int k2 = 0; k2 < 2; k2++) {
        const int pos = (k2 * 4 + quad) ^ (l16 & 7);  // drow&7 == l16&7
        const bf16x8 vf = *(const bf16x8*)((const char*)Vs + BUF * 16384 +
                                           (dg * 16 + l16) * 128 + pos * 16);
        yacc[dg] = MFMA16x16x32(pf[k2], vf, yacc[dg], 0, 0, 0);
      }
    }
    __builtin_amdgcn_s_setprio(0);
    __asm__ volatile("s_barrier" ::: "memory");  // 1-BUF free to overwrite
  };

  const std::integral_constant<int, 0> c0{};
  const std::integral_constant<int, 1> c1{};

  for (int sidx = 0; sidx < 2; ++sidx) {
    const int xb = sidx ? pr : (31 - pr);  // long strip first, then short
    const int q0 = xb * 64;
    const int nt = xb + 1;

    bf16x8 qf[4];
    {
      const bf16* qbase = qn + ((size_t)(b * T_ + q0 + w * 16 + l16) * H_ + h) * 128;
#pragma unroll
      for (int ks = 0; ks < 4; ks++) qf[ks] = *(const bf16x8*)(qbase + ks * 32 + quad * 8);
    }
    f32x4 yacc[8];
#pragma unroll
    for (int i = 0; i < 8; i++) yacc[i] = f32x4{0.f, 0.f, 0.f, 0.f};
    float lrow[4] = {0.f, 0.f, 0.f, 0.f};

    stage(c0, 0);  // prologue prefetch into buf0
    int it = 0;
    for (; it + 2 <= nt; it += 2) {
      body(c0, it, nt, xb, qf, yacc, lrow);
      body(c1, it + 1, nt, xb, qf, yacc, lrow);
    }
    if (it < nt) body(c0, it, nt, xb, qf, yacc, lrow);  // odd tail uses buf0

    // epilogue: reduce per-lane l partials across the 16 cols once, then scale
#pragma unroll
    for (int off = 1; off < 16; off <<= 1)
#pragma unroll
      for (int r = 0; r < 4; r++) lrow[r] += __shfl_xor(lrow[r], off);
#pragma unroll
    for (int r = 0; r < 4; r++) {
      float inv = 1.0f / lrow[r];
      size_t qrow = (size_t)(b * T_ + q0 + w * 16 + quad * 4 + r);
      bf16* outp = y + qrow * 2048 + h * 128;
#pragma unroll
      for (int dg = 0; dg < 8; dg++)
        outp[dg * 16 + l16] = __float2bfloat16(yacc[dg][r] * inv);
    }
  }
}

// ---------------------------------------------------------------- launcher
extern "C" void kernel_launch(void* const* d_in, const int* in_sizes, int n_in,
                              void* d_out, int out_size, void* d_ws, size_t ws_size,
                              hipStream_t stream) {
  (void)in_sizes; (void)n_in; (void)out_size; (void)ws_size;
  const float* x    = (const float*)d_in[0];
  const float* cosp = (const float*)d_in[1];
  const float* sinp = (const float*)d_in[2];
  const float* wqd  = (const float*)d_in[3];
  const float* wqu  = (const float*)d_in[4];
  const float* wkvd = (const float*)d_in[5];
  const float* wkvu = (const float*)d_in[6];
  const float* wo   = (const float*)d_in[7];
  float* out = (float*)d_out;

  char* ws = (char*)d_ws;
  size_t off = 0;
  auto alloc = [&](size_t elems) { bf16* p = (bf16*)(ws + off); off += elems * 2; return p; };
  bf16* xb      = alloc((size_t)4096 * 2048);
  bf16* wqdB    = alloc((size_t)1536 * 2048);  // wqdB+wkvdB contiguous: fused (2048,2048) W
  bf16* wkvdB   = alloc((size_t)512 * 2048);
  bf16* wquB    = alloc((size_t)2048 * 1536);
  bf16* wkvuB   = alloc((size_t)4096 * 512);
  bf16* woB     = alloc((size_t)2048 * 2048);
  bf16* qkvdown = alloc((size_t)4096 * 2048);  // cols 0..1535 = qdown, 1536..2047 = kvdown
  bf16* qraw    = alloc((size_t)4096 * 2048);
  bf16* kvraw   = alloc((size_t)4096 * 4096);  // only K-halves written/used
  bf16* qnb     = alloc((size_t)4096 * 16 * 128);
  bf16* knb     = alloc((size_t)4096 * 16 * 128);
  bf16* vTb     = alloc((size_t)2 * 16 * 128 * 2048);
  bf16* yb      = alloc((size_t)4096 * 2048);

  // one fused cast launch for all six fp32->bf16 conversions
  CastArgs ca;
  const float* srcs[6] = {x, wqd, wkvd, wqu, wkvu, wo};
  bf16* dsts[6]        = {xb, wqdB, wkvdB, wquB, wkvuB, woB};
  size_t cnts[6] = {(size_t)4096 * 2048, (size_t)1536 * 2048, (size_t)512 * 2048,
                    (size_t)2048 * 1536, (size_t)4096 * 512,  (size_t)2048 * 2048};
  unsigned cum = 0;
  for (int i = 0; i < 6; i++) {
    ca.src[i] = (const float4*)srcs[i];
    ca.dst[i] = (ushort4*)dsts[i];
    cum += (unsigned)(cnts[i] / 4);
    ca.bound[i] = cum;
  }
  f2bf_multi<<<dim3((cum + 255) / 256), 256, 0, stream>>>(ca);

  // fused down-proj: (4096 x 2048) = x @ [wq_down; wkv_down]^T
  gemm8p<bf16, false><<<dim3(16, 8), 512, 0, stream>>>(
      xb, wqdB, qkvdown, nullptr, 2048, 2048, 2048);
  // q up-projection (strided A)
  gemm8p<bf16, false><<<dim3(16, 8), 512, 0, stream>>>(
      qkvdown, wquB, qraw, nullptr, 2048, 1536, 2048);
  // kv up-projection with fused K-half / V-transpose epilogue
  gemm8p<bf16, true><<<dim3(16, 16), 512, 0, stream>>>(
      qkvdown + 1536, wkvuB, kvraw, vTb, 4096, 512, 2048);
  rope_rms<<<dim3(4096, 4), 256, 0, stream>>>(qraw, kvraw, cosp, sinp, qnb, knb);
  attn_kernel<<<dim3(32, 16), 256, 0, stream>>>(qnb, knb, vTb, yb);
  gemm8p<float, false><<<dim3(16, 8), 512, 0, stream>>>(
      yb, woB, out, nullptr, 2048, 2048, 2048);
}

// Round 8
// 397.119 us; speedup vs baseline: 1.1361x; 1.0078x over previous
//
#include <hip/hip_runtime.h>
#include <hip/hip_bf16.h>
#include <math.h>
#include <type_traits>

#define AS1 __attribute__((address_space(1)))
#define AS3 __attribute__((address_space(3)))

typedef __bf16  bf16x8 __attribute__((ext_vector_type(8)));
typedef float   f32x4  __attribute__((ext_vector_type(4)));
typedef __hip_bfloat16 bf16;

#define MFMA16x16x32 __builtin_amdgcn_mfma_f32_16x16x32_bf16

__device__ __forceinline__ void gload16(const void* g, void* l) {
  // async global->LDS, 16B per lane; LDS dest = wave-uniform base + lane*16
  __builtin_amdgcn_global_load_lds((const AS1 void*)g, (AS3 void*)l, 16, 0, 0);
}

__device__ __forceinline__ unsigned short bfbits(float v) {
  return __builtin_bit_cast(unsigned short, __float2bfloat16(v));
}

#define LGKM0 __asm__ volatile("s_waitcnt lgkmcnt(0)" ::: "memory")
#define BARRIER __builtin_amdgcn_s_barrier()
#define VMCNT(n) __asm__ volatile("s_waitcnt vmcnt(" #n ")" ::: "memory")

// ---------------------------------------------------------------- fused fp32 -> bf16 casts
struct CastArgs {
  const float4* src[6];
  ushort4* dst[6];
  unsigned bound[6];  // cumulative float4 counts
};

__global__ __launch_bounds__(256) void f2bf_multi(CastArgs a) {
  unsigned i = blockIdx.x * 256 + threadIdx.x;
  if (i >= a.bound[5]) return;
  unsigned lo = 0;
  int s = 0;
#pragma unroll
  for (int k = 0; k < 5; k++) {
    if (i >= a.bound[k]) { s = k + 1; lo = a.bound[k]; }
  }
  unsigned idx = i - lo;
  float4 v = a.src[s][idx];
  ushort4 o;
  o.x = bfbits(v.x); o.y = bfbits(v.y); o.z = bfbits(v.z); o.w = bfbits(v.w);
  a.dst[s][idx] = o;
}

// ---------------------------------------------------------------- split-K merge: out = p0 + p1
template <typename OutT>
__global__ __launch_bounds__(256) void addmerge(const float4* __restrict__ p0,
                                                const float4* __restrict__ p1,
                                                OutT* __restrict__ out, unsigned n4) {
  for (unsigned i = blockIdx.x * 256 + threadIdx.x; i < n4; i += gridDim.x * 256) {
    float4 a = p0[i], b = p1[i];
    if constexpr (std::is_same<OutT, float>::value) {
      float4 o;
      o.x = a.x + b.x; o.y = a.y + b.y; o.z = a.z + b.z; o.w = a.w + b.w;
      ((float4*)out)[i] = o;
    } else {
      ushort4 o;
      o.x = bfbits(a.x + b.x); o.y = bfbits(a.y + b.y);
      o.z = bfbits(a.z + b.z); o.w = bfbits(a.w + b.w);
      ((ushort4*)out)[i] = o;
    }
  }
}

// ---------------------------------------------------------------- 256x256 8-phase GEMM
// C = A*W^T.  A:(M,K) bf16 stride lda.  W:(N,K) bf16 stride ldb.  8 waves (2Mx4N),
// BK=64, 2 K-tiles/iteration, 8 phases x 16 MFMA.  LDS 128 KiB, slot = kt&1.
// T2: chunk^(row&7) swizzle via pre-swizzled global sources (linear gload dest).
// T4 re-staggered (R8): stages at earliest slot-free phase -> min 2.5-phase
// latency cover; vmcnt(4) at P2/P6 retires exactly the K-tile needed next.
//   P0: kt1.A1 | P1: kt2.B0 | P2: kt2.A0 | P3: kt2.B1 | P4: kt2.A1
//   P5: kt3.B0 | P6: kt3.A0 | P7: kt3.B1   (kt3.A1 lands at next-P0)
// SPLIT: blockIdx.z selects K-half; f32 partial to p0/p1 (merged by addmerge).
template <typename OutT, bool KVUP, bool SPLIT>
__global__ __launch_bounds__(512, 2) void gemm8p(const bf16* __restrict__ A,
                                                 const bf16* __restrict__ W,
                                                 OutT* __restrict__ Cp,
                                                 bf16* __restrict__ vT,
                                                 float* __restrict__ pp0,
                                                 float* __restrict__ pp1,
                                                 int N, int Klen, int lda, int ldb) {
  __shared__ __align__(16) char lds[131072];
  const int t = threadIdx.x, w = t >> 6, lane = t & 63;
  const int quad = lane >> 4, l16 = lane & 15;
  const int wr = w >> 2, wc = w & 3;  // 2x4 wave grid; wave tile 128x64
  const size_t m0 = (size_t)blockIdx.x * 256;
  const size_t n0 = (size_t)blockIdx.y * 256;
  if constexpr (SPLIT) {
    const size_t zo = (size_t)blockIdx.z * Klen;
    A += zo; W += zo;  // column offset into full-stride rows
  }
  const int NI = Klen >> 7;  // iterations (2 K-tiles each)

  // staging bases: thread covers (row = h*128 + sweep*64 + w*8 + lane>>3,
  // chunk = lane&7), source chunk pre-swizzled by ^(row&7) = ^(lane>>3 & 7)
  const int srow = w * 8 + (lane >> 3);
  const int schunk = (lane & 7) ^ ((lane >> 3) & 7);
  const bf16* aS = A + (m0 + srow) * (size_t)lda + schunk * 8;
  const bf16* bS = W + (n0 + srow) * (size_t)ldb + schunk * 8;

  auto stageA = [&](int kt, int h) {
    const bf16* src = aS + (size_t)(h * 128) * lda + kt * 64;
    char* dst = lds + (kt & 1) * 32768 + h * 16384 + w * 1024;
    gload16(src, dst);                          // sweep 0 (rows +0..63)
    gload16(src + (size_t)64 * lda, dst + 8192);// sweep 1 (rows +64..127)
  };
  auto stageB = [&](int kt, int h) {
    const bf16* src = bS + (size_t)(h * 128) * ldb + kt * 64;
    char* dst = lds + 65536 + (kt & 1) * 32768 + h * 16384 + w * 1024;
    gload16(src, dst);
    gload16(src + (size_t)64 * ldb, dst + 8192);
  };

  // per-lane read bases; chunk = (kh*4+quad)^(l16&7) (row&7 == l16&7)
  const int cq0 = ((quad) ^ (l16 & 7)) * 16;
  const int cq1 = ((4 + quad) ^ (l16 & 7)) * 16;
  const char* aRb = lds + wr * 16384 + l16 * 128;
  const char* bRb = lds + 65536 + (wc >> 1) * 16384 + ((wc & 1) * 64 + l16) * 128;
  auto rdA = [&](int sl, int mf, int kh) -> bf16x8 {
    return *(const bf16x8*)(aRb + sl * 32768 + mf * 2048 + (kh ? cq1 : cq0));
  };
  auto rdB = [&](int sl, int nf, int kh) -> bf16x8 {
    return *(const bf16x8*)(bRb + sl * 32768 + nf * 2048 + (kh ? cq1 : cq0));
  };

  bf16x8 aR[8][2], bR[4][2];
  f32x4 acc[8][4];
#pragma unroll
  for (int i = 0; i < 8; i++)
#pragma unroll
    for (int j = 0; j < 4; j++) acc[i][j] = f32x4{0.f, 0.f, 0.f, 0.f};

  auto cluster = [&](int mh, int nh) {  // 4mf x 2nf x 2kh = 16 MFMA
    __builtin_amdgcn_s_setprio(1);
#pragma unroll
    for (int m2 = 0; m2 < 4; ++m2)
#pragma unroll
      for (int n2 = 0; n2 < 2; ++n2)
#pragma unroll
        for (int kh = 0; kh < 2; ++kh)
          acc[mh * 4 + m2][nh * 2 + n2] =
              MFMA16x16x32(aR[mh * 4 + m2][kh], bR[nh * 2 + n2][kh],
                           acc[mh * 4 + m2][nh * 2 + n2], 0, 0, 0);
    __builtin_amdgcn_s_setprio(0);
  };

  // ---- prologue: kt0 fully + kt1 {B0, A0, B1}; kt1.A1 arrives at P0 of iter 0
  stageA(0, 0); stageA(0, 1); stageB(0, 0); stageB(0, 1);
  stageB(1, 0); stageA(1, 0); stageB(1, 1);
  VMCNT(6);  // retire kt0's 8; kt1's 6 stay in flight
  BARRIER;
#pragma unroll
  for (int mf = 0; mf < 4; ++mf)
#pragma unroll
    for (int kh = 0; kh < 2; ++kh) aR[mf][kh] = rdA(0, mf, kh);
#pragma unroll
  for (int nf = 0; nf < 2; ++nf)
#pragma unroll
    for (int kh = 0; kh < 2; ++kh) bR[nf][kh] = rdB(0, nf, kh);

  for (int i = 0; i < NI; ++i) {
    const int kt1 = 2 * i + 1, kt2 = 2 * i + 2, kt3 = 2 * i + 3;
    const bool hn = (i + 1 < NI);

    // P0: rd kt0.b23 | stage kt1.A1 (always; kt1 always exists) | c(0,0)
#pragma unroll
    for (int kh = 0; kh < 2; ++kh) { bR[2][kh] = rdB(0, 2, kh); bR[3][kh] = rdB(0, 3, kh); }
    stageA(kt1, 1);
    BARRIER; LGKM0;
    cluster(0, 0);
    BARRIER;

    // P1: rd kt0.a47 | stage kt2.B0 | c(0,1)
#pragma unroll
    for (int mf = 0; mf < 4; ++mf)
#pragma unroll
      for (int kh = 0; kh < 2; ++kh) aR[4 + mf][kh] = rdA(0, 4 + mf, kh);
    if (hn) stageB(kt2, 0);
    BARRIER; LGKM0;
    cluster(0, 1);
    BARRIER;

    // P2: stage kt2.A0 | c(1,0) | vmcnt(4): retires kt1's 8 before P3 reads
    if (hn) stageA(kt2, 0);
    BARRIER; LGKM0;
    cluster(1, 0);
    if (hn) { VMCNT(4); } else { VMCNT(0); }
    BARRIER;

    // P3: rd kt1.a03 + kt1.b01 | stage kt2.B1 | c(1,1)
#pragma unroll
    for (int mf = 0; mf < 4; ++mf)
#pragma unroll
      for (int kh = 0; kh < 2; ++kh) aR[mf][kh] = rdA(1, mf, kh);
#pragma unroll
    for (int nf = 0; nf < 2; ++nf)
#pragma unroll
      for (int kh = 0; kh < 2; ++kh) bR[nf][kh] = rdB(1, nf, kh);
    if (hn) stageB(kt2, 1);
    BARRIER; LGKM0;
    cluster(1, 1);
    BARRIER;

    // P4: rd kt1.b23 | stage kt2.A1 | c(0,0)
#pragma unroll
    for (int kh = 0; kh < 2; ++kh) { bR[2][kh] = rdB(1, 2, kh); bR[3][kh] = rdB(1, 3, kh); }
    if (hn) stageA(kt2, 1);
    BARRIER; LGKM0;
    cluster(0, 0);
    BARRIER;

    // P5: rd kt1.a47 | stage kt3.B0 | c(0,1)
#pragma unroll
    for (int mf = 0; mf < 4; ++mf)
#pragma unroll
      for (int kh = 0; kh < 2; ++kh) aR[4 + mf][kh] = rdA(1, 4 + mf, kh);
    if (hn) stageB(kt3, 0);
    BARRIER; LGKM0;
    cluster(0, 1);
    BARRIER;

    // P6: stage kt3.A0 | c(1,0) | vmcnt(4): retires kt2's 8 before P7 reads
    if (hn) stageA(kt3, 0);
    BARRIER; LGKM0;
    cluster(1, 0);
    if (hn) { VMCNT(4); }
    BARRIER;

    // P7: rd kt2.a03 + kt2.b01 | stage kt3.B1 | c(1,1)
    if (hn) {
#pragma unroll
      for (int mf = 0; mf < 4; ++mf)
#pragma unroll
        for (int kh = 0; kh < 2; ++kh) aR[mf][kh] = rdA(0, mf, kh);
#pragma unroll
      for (int nf = 0; nf < 2; ++nf)
#pragma unroll
        for (int kh = 0; kh < 2; ++kh) bR[nf][kh] = rdB(0, nf, kh);
      stageB(kt3, 1);
    }
    BARRIER; LGKM0;
    cluster(1, 1);
    BARRIER;
  }

  // ---- epilogue
  if constexpr (SPLIT) {
    float* dst = blockIdx.z ? pp1 : pp0;
#pragma unroll
    for (int mf = 0; mf < 8; ++mf)
#pragma unroll
      for (int nf = 0; nf < 4; ++nf)
#pragma unroll
        for (int r = 0; r < 4; ++r) {
          size_t row = m0 + wr * 128 + mf * 16 + quad * 4 + r;
          size_t col = n0 + wc * 64 + nf * 16 + l16;
          dst[row * N + col] = acc[mf][nf][r];
        }
  } else if constexpr (!KVUP) {
#pragma unroll
    for (int mf = 0; mf < 8; ++mf)
#pragma unroll
      for (int nf = 0; nf < 4; ++nf)
#pragma unroll
        for (int r = 0; r < 4; ++r) {
          size_t row = m0 + wr * 128 + mf * 16 + quad * 4 + r;
          size_t col = n0 + wc * 64 + nf * 16 + l16;
          float v = acc[mf][nf][r];
          if constexpr (std::is_same<OutT, float>::value)
            Cp[row * N + col] = v;
          else
            Cp[row * N + col] = __float2bfloat16(v);
        }
  } else {
    // n-tile 256 = one head; wc 0,1 -> K-half (cols 0-127); wc 2,3 -> V-half
    const int head = (int)(n0 >> 8);
    if (wc < 2) {
#pragma unroll
      for (int mf = 0; mf < 8; ++mf)
#pragma unroll
        for (int nf = 0; nf < 4; ++nf)
#pragma unroll
          for (int r = 0; r < 4; ++r) {
            size_t row = m0 + wr * 128 + mf * 16 + quad * 4 + r;
            size_t col = n0 + wc * 64 + nf * 16 + l16;
            Cp[row * 4096 + col] = __float2bfloat16(acc[mf][nf][r]);
          }
    } else {
#pragma unroll
      for (int mf = 0; mf < 8; ++mf) {
        size_t row = m0 + wr * 128 + mf * 16 + quad * 4;  // +r all same b-block
        int bb = (int)(row >> 11), tloc = (int)(row & 2047);
#pragma unroll
        for (int nf = 0; nf < 4; ++nf) {
          int d = (wc - 2) * 64 + nf * 16 + l16;
          ushort4 v4;
          v4.x = bfbits(acc[mf][nf][0]);
          v4.y = bfbits(acc[mf][nf][1]);
          v4.z = bfbits(acc[mf][nf][2]);
          v4.w = bfbits(acc[mf][nf][3]);
          *(ushort4*)(vT + ((size_t)(bb * 16 + head) * 128 + d) * 2048 + tloc) = v4;
        }
      }
    }
  }
}

// ---------------------------------------------------------------- RoPE + RMSNorm
__global__ __launch_bounds__(256) void rope_rms(const bf16* __restrict__ qraw,
                                                const bf16* __restrict__ kvraw,
                                                const float* __restrict__ cosp,
                                                const float* __restrict__ sinp,
                                                bf16* __restrict__ qn,
                                                bf16* __restrict__ kn) {
  const int bt = blockIdx.x;
  const int w = threadIdx.x >> 6, lane = threadIdx.x & 63;
  const int h = blockIdx.y * 4 + w;
  const int tt = bt & 2047;  // T = 2048
  const float c = cosp[tt * 32 + (lane & 31)];
  const float s = sinp[tt * 32 + (lane & 31)];
  const float inv128 = 1.0f / 128.0f;
  const float eps = 1.1920929e-7f;

  // Q
  {
    const bf16* base = qraw + (size_t)bt * 2048 + h * 128;
    float a = (float)base[lane];
    float o = (float)base[64 + lane];
    float partner = __shfl_xor(o, 32);
    float orope = (lane < 32) ? (o * c + partner * s) : (o * c - partner * s);
    float ss = a * a + orope * orope;
#pragma unroll
    for (int off = 1; off < 64; off <<= 1) ss += __shfl_xor(ss, off);
    float rn = rsqrtf(ss * inv128 + eps);
    bf16* outp = qn + ((size_t)bt * 16 + h) * 128;
    outp[lane] = __float2bfloat16(a * rn);
    outp[64 + lane] = __float2bfloat16(orope * rn);
  }
  // K
  {
    const bf16* base = kvraw + (size_t)bt * 4096 + h * 256;
    float a = (float)base[lane];
    float o = (float)base[64 + lane];
    float partner = __shfl_xor(o, 32);
    float orope = (lane < 32) ? (o * c + partner * s) : (o * c - partner * s);
    float ss = a * a + orope * orope;
#pragma unroll
    for (int off = 1; off < 64; off <<= 1) ss += __shfl_xor(ss, off);
    float rn = rsqrtf(ss * inv128 + eps);
    bf16* outp = kn + ((size_t)bt * 16 + h) * 128;
    outp[lane] = __float2bfloat16(a * rn);
    outp[64 + lane] = __float2bfloat16(orope * rn);
  }
}

// ---------------------------------------------------------------- flash attention
// R3 version (best verified: 75.2 us): double-buffer K/V, prefetch + vmcnt(8),
// uniform pairing {31-pr, pr} = 33 tiles/block, KV loop unrolled x2 with
// compile-time buffer index, hoisted staging bases, setprio on MFMA clusters.
__global__ __launch_bounds__(256, 2) void attn_kernel(const bf16* __restrict__ qn,
                                                      const bf16* __restrict__ kn,
                                                      const bf16* __restrict__ vT,
                                                      bf16* __restrict__ y) {
  __shared__ __align__(16) bf16 Ks[2 * 64 * 128];   // [buf][s][d-chunks swizzled] 32 KB
  __shared__ __align__(16) bf16 Vs[2 * 128 * 64];   // [buf][d][s-chunks swizzled] 32 KB
  __shared__ __align__(16) bf16 Ps[4 * 16 * 64];    // per-wave P, swizzled         8 KB
  const int t = threadIdx.x, w = t >> 6, lane = t & 63;
  const int quad = lane >> 4, l16 = lane & 15;
  const int b = blockIdx.x >> 4, h = blockIdx.x & 15;
  const int pr = (int)blockIdx.y;  // 0..15
  const int T_ = 2048, H_ = 16;
  // p = exp2(sacc * K1 + K2) = e^(sacc/sqrt(128) - 12);  |q.k|/sqrt(128) <= sqrt(128) < 12
  const float K1 = 0.08838834764831845f * 1.4426950408889634f;
  const float K2 = -12.0f * 1.4426950408889634f;

  // per-lane tile-invariant staging bases
  const int cgk = l16 ^ ((w * 4 + quad) & 7);
  const char* kg0 = (const char*)(kn + ((size_t)(b * T_) * H_ + h) * 128)
                    + (size_t)(w * 4 + quad) * 4096 + (size_t)cgk * 16;
  const int vrow = w * 8 + (lane >> 3);
  const int cgv = (lane & 7) ^ (vrow & 7);
  const char* vg0 = (const char*)(vT + ((size_t)(b * H_ + h) * 128 + vrow) * T_)
                    + (size_t)cgv * 16;

  // stage K/V tile it2 into LDS buffer BUF (compile-time)
  auto stage = [&](auto bufc, int it2) {
    constexpr int BUF = decltype(bufc)::value;
    const size_t koff = (size_t)it2 * 262144;  // 64 rows * 4096 B
    const size_t voff = (size_t)it2 * 128;     // 64 cols * 2 B
#pragma unroll
    for (int is = 0; is < 4; ++is)
      gload16(kg0 + koff + (size_t)is * 65536,
              (char*)Ks + BUF * 16384 + is * 4096 + w * 1024);
#pragma unroll
    for (int is = 0; is < 4; ++is)
      gload16(vg0 + voff + (size_t)is * 131072,
              (char*)Vs + BUF * 16384 + is * 4096 + w * 1024);
  };

  // one KV tile: prefetch next into 1-BUF, sync, QK^T, softmax, P->LDS, PV
  auto body = [&](auto bufc, int it, int nt, int xb,
                  bf16x8* qf, f32x4* yacc, float* lrow) {
    constexpr int BUF = decltype(bufc)::value;
    if (it + 1 < nt) {
      stage(std::integral_constant<int, 1 - BUF>{}, it + 1);
      __asm__ volatile("s_waitcnt vmcnt(8)" ::: "memory");  // tile-it loads done
    } else {
      __asm__ volatile("s_waitcnt vmcnt(0)" ::: "memory");
    }
    __asm__ volatile("s_barrier" ::: "memory");

    // S = Q K^T   (kf addr: BUF/cg in offset-immediate, one vaddr per ks)
    f32x4 sacc[4];
#pragma unroll
    for (int cg = 0; cg < 4; cg++) sacc[cg] = f32x4{0.f, 0.f, 0.f, 0.f};
    __builtin_amdgcn_s_setprio(1);
#pragma unroll
    for (int cg = 0; cg < 4; ++cg) {
#pragma unroll
      for (int ks = 0; ks < 4; ++ks) {
        const int pos = (ks * 4 + quad) ^ (l16 & 7);  // srow&7 == l16&7
        const bf16x8 kf = *(const bf16x8*)((const char*)Ks + BUF * 16384 +
                                           (cg * 16 + l16) * 256 + pos * 16);
        sacc[cg] = MFMA16x16x32(qf[ks], kf, sacc[cg], 0, 0, 0);
      }
    }
    __builtin_amdgcn_s_setprio(0);

    // fixed-max softmax: p = exp2(s*K1 + K2); per-lane partial l
    const bool diag = (it == xb);
    float p[4][4];
#pragma unroll
    for (int cg = 0; cg < 4; ++cg)
#pragma unroll
      for (int r = 0; r < 4; ++r) {
        float e;
        if (diag && (cg * 16 + l16 > w * 16 + quad * 4 + r))
          e = 0.0f;
        else
          e = exp2f(fmaf(sacc[cg][r], K1, K2));
        p[cg][r] = e;
        lrow[r] += e;
      }

    // P: C-layout -> LDS (stride 64, chunk-XOR swizzle) -> A-layout
#pragma unroll
    for (int cg = 0; cg < 4; cg++)
#pragma unroll
      for (int r = 0; r < 4; r++) {
        const int row = quad * 4 + r;
        const int col = cg * 16 + l16;
        Ps[w * 1024 + row * 64 + (((col >> 3) ^ (row & 7)) << 3) + (col & 7)] =
            __float2bfloat16(p[cg][r]);
      }
    __asm__ volatile("s_waitcnt lgkmcnt(0)" ::: "memory");

    bf16x8 pf[2];
#pragma unroll
    for (int k2 = 0; k2 < 2; k2++)
      pf[k2] = *(const bf16x8*)(&Ps[w * 1024 + l16 * 64 +
                                    (((k2 * 4 + quad) ^ (l16 & 7)) << 3)]);
    __builtin_amdgcn_s_setprio(1);
#pragma unroll
    for (int dg = 0; dg < 8; dg++) {
#pragma unroll
      for (int k2 = 0; k2 < 2; k2++) {
        const int pos = (k2 * 4 + quad) ^ (l16 & 7);  // drow&7 == l16&7
        const bf16x8 vf = *(const bf16x8*)((const char*)Vs + BUF * 16384 +
                                           (dg * 16 + l16) * 128 + pos * 16);
        yacc[dg] = MFMA16x16x32(pf[k2], vf, yacc[dg], 0, 0, 0);
      }
    }
    __builtin_amdgcn_s_setprio(0);
    __asm__ volatile("s_barrier" ::: "memory");  // 1-BUF free to overwrite
  };

  const std::integral_constant<int, 0> c0{};
  const std::integral_constant<int, 1> c1{};

  for (int sidx = 0; sidx < 2; ++sidx) {
    const int xb = sidx ? pr : (31 - pr);  // long strip first, then short
    const int q0 = xb * 64;
    const int nt = xb + 1;

    bf16x8 qf[4];
    {
      const bf16* qbase = qn + ((size_t)(b * T_ + q0 + w * 16 + l16) * H_ + h) * 128;
#pragma unroll
      for (int ks = 0; ks < 4; ks++) qf[ks] = *(const bf16x8*)(qbase + ks * 32 + quad * 8);
    }
    f32x4 yacc[8];
#pragma unroll
    for (int i = 0; i < 8; i++) yacc[i] = f32x4{0.f, 0.f, 0.f, 0.f};
    float lrow[4] = {0.f, 0.f, 0.f, 0.f};

    stage(c0, 0);  // prologue prefetch into buf0
    int it = 0;
    for (; it + 2 <= nt; it += 2) {
      body(c0, it, nt, xb, qf, yacc, lrow);
      body(c1, it + 1, nt, xb, qf, yacc, lrow);
    }
    if (it < nt) body(c0, it, nt, xb, qf, yacc, lrow);  // odd tail uses buf0

    // epilogue: reduce per-lane l partials across the 16 cols once, then scale
#pragma unroll
    for (int off = 1; off < 16; off <<= 1)
#pragma unroll
      for (int r = 0; r < 4; r++) lrow[r] += __shfl_xor(lrow[r], off);
#pragma unroll
    for (int r = 0; r < 4; r++) {
      float inv = 1.0f / lrow[r];
      size_t qrow = (size_t)(b * T_ + q0 + w * 16 + quad * 4 + r);
      bf16* outp = y + qrow * 2048 + h * 128;
#pragma unroll
      for (int dg = 0; dg < 8; dg++)
        outp[dg * 16 + l16] = __float2bfloat16(yacc[dg][r] * inv);
    }
  }
}

// ---------------------------------------------------------------- launcher
extern "C" void kernel_launch(void* const* d_in, const int* in_sizes, int n_in,
                              void* d_out, int out_size, void* d_ws, size_t ws_size,
                              hipStream_t stream) {
  (void)in_sizes; (void)n_in; (void)out_size; (void)ws_size;
  const float* x    = (const float*)d_in[0];
  const float* cosp = (const float*)d_in[1];
  const float* sinp = (const float*)d_in[2];
  const float* wqd  = (const float*)d_in[3];
  const float* wqu  = (const float*)d_in[4];
  const float* wkvd = (const float*)d_in[5];
  const float* wkvu = (const float*)d_in[6];
  const float* wo   = (const float*)d_in[7];
  float* out = (float*)d_out;

  char* ws = (char*)d_ws;
  size_t off = 0;
  auto alloc = [&](size_t elems) { bf16* p = (bf16*)(ws + off); off += elems * 2; return p; };
  bf16* xb      = alloc((size_t)4096 * 2048);
  bf16* wqdB    = alloc((size_t)1536 * 2048);  // wqdB+wkvdB contiguous: fused (2048,2048) W
  bf16* wkvdB   = alloc((size_t)512 * 2048);
  bf16* wquB    = alloc((size_t)2048 * 1536);
  bf16* wkvuB   = alloc((size_t)4096 * 512);
  bf16* woB     = alloc((size_t)2048 * 2048);
  bf16* qkvdown = alloc((size_t)4096 * 2048);  // cols 0..1535 = qdown, 1536..2047 = kvdown
  bf16* qraw    = alloc((size_t)4096 * 2048);
  bf16* kvraw   = alloc((size_t)4096 * 4096);  // K-halves used by rope; also split-K scratch p0
  bf16* qnb     = alloc((size_t)4096 * 16 * 128);
  bf16* knb     = alloc((size_t)4096 * 16 * 128);  // qnb+knb contiguous: split-K scratch p1
  bf16* vTb     = alloc((size_t)2 * 16 * 128 * 2048);
  bf16* yb      = alloc((size_t)4096 * 2048);

  // split-K f32 partial buffers alias dead regions at each use point:
  //  - down/qup: kvraw + (qnb..knb) are written only later (kvup / rope_rms)
  //  - wo: kvraw + qnb dead after attn
  float* pp0 = (float*)kvraw;   // 33.6 MB
  float* pp1 = (float*)qnb;     // qnb+knb contiguous = 33.6 MB

  // one fused cast launch for all six fp32->bf16 conversions
  CastArgs ca;
  const float* srcs[6] = {x, wqd, wkvd, wqu, wkvu, wo};
  bf16* dsts[6]        = {xb, wqdB, wkvdB, wquB, wkvuB, woB};
  size_t cnts[6] = {(size_t)4096 * 2048, (size_t)1536 * 2048, (size_t)512 * 2048,
                    (size_t)2048 * 1536, (size_t)4096 * 512,  (size_t)2048 * 2048};
  unsigned cum = 0;
  for (int i = 0; i < 6; i++) {
    ca.src[i] = (const float4*)srcs[i];
    ca.dst[i] = (ushort4*)dsts[i];
    cum += (unsigned)(cnts[i] / 4);
    ca.bound[i] = cum;
  }
  f2bf_multi<<<dim3((cum + 255) / 256), 256, 0, stream>>>(ca);

  const unsigned n4 = (unsigned)((size_t)4096 * 2048 / 4);

  // fused down-proj: (4096 x 2048) = x @ [wq_down; wkv_down]^T, split-K x2
  gemm8p<float, false, true><<<dim3(16, 8, 2), 512, 0, stream>>>(
      xb, wqdB, (float*)nullptr, nullptr, pp0, pp1, 2048, 1024, 2048, 2048);
  addmerge<bf16><<<dim3(2048), 256, 0, stream>>>((const float4*)pp0, (const float4*)pp1,
                                                 qkvdown, n4);
  // q up-projection (strided A), split-K x2 (K=1536 -> 768 per half)
  gemm8p<float, false, true><<<dim3(16, 8, 2), 512, 0, stream>>>(
      qkvdown, wquB, (float*)nullptr, nullptr, pp0, pp1, 2048, 768, 2048, 1536);
  addmerge<bf16><<<dim3(2048), 256, 0, stream>>>((const float4*)pp0, (const float4*)pp1,
                                                 qraw, n4);
  // kv up-projection with fused K-half / V-transpose epilogue (full machine already)
  gemm8p<bf16, true, false><<<dim3(16, 16), 512, 0, stream>>>(
      qkvdown + 1536, wkvuB, kvraw, vTb, nullptr, nullptr, 4096, 512, 2048, 512);
  rope_rms<<<dim3(4096, 4), 256, 0, stream>>>(qraw, kvraw, cosp, sinp, qnb, knb);
  attn_kernel<<<dim3(32, 16), 256, 0, stream>>>(qnb, knb, vTb, yb);
  // output projection, split-K x2; partial scratch (kvraw/qnb) dead after attn
  gemm8p<float, false, true><<<dim3(16, 8, 2), 512, 0, stream>>>(
      yb, woB, (float*)nullptr, nullptr, pp0, pp1, 2048, 1024, 2048, 2048);
  addmerge<float><<<dim3(2048), 256, 0, stream>>>((const float4*)pp0, (const float4*)pp1,
                                                  out, n4);
}

// Round 10
// 369.287 us; speedup vs baseline: 1.2217x; 1.0754x over previous
//
#include <hip/hip_runtime.h>
#include <hip/hip_bf16.h>
#include <math.h>
#include <type_traits>

#define AS1 __attribute__((address_space(1)))
#define AS3 __attribute__((address_space(3)))

typedef __bf16  bf16x8 __attribute__((ext_vector_type(8)));
typedef float   f32x4  __attribute__((ext_vector_type(4)));
typedef __hip_bfloat16 bf16;

#define MFMA16x16x32 __builtin_amdgcn_mfma_f32_16x16x32_bf16

__device__ __forceinline__ void gload16(const void* g, void* l) {
  // async global->LDS, 16B per lane; LDS dest = wave-uniform base + lane*16
  __builtin_amdgcn_global_load_lds((const AS1 void*)g, (AS3 void*)l, 16, 0, 0);
}

__device__ __forceinline__ unsigned short bfbits(float v) {
  return __builtin_bit_cast(unsigned short, __float2bfloat16(v));
}

// ---------------------------------------------------------------- fused fp32 -> bf16 casts
struct CastArgs {
  const float4* src[6];
  ushort4* dst[6];
  unsigned bound[6];  // cumulative float4 counts
};

__global__ __launch_bounds__(256) void f2bf_multi(CastArgs a) {
  unsigned i = blockIdx.x * 256 + threadIdx.x;
  if (i >= a.bound[5]) return;
  unsigned lo = 0;
  int s = 0;
#pragma unroll
  for (int k = 0; k < 5; k++) {
    if (i >= a.bound[k]) { s = k + 1; lo = a.bound[k]; }
  }
  unsigned idx = i - lo;
  float4 v = a.src[s][idx];
  ushort4 o;
  o.x = bfbits(v.x); o.y = bfbits(v.y); o.z = bfbits(v.z); o.w = bfbits(v.w);
  a.dst[s][idx] = o;
}

// ---------------------------------------------------------------- GEMM  C = A * W^T  (128x128, BK=64)
// Proven R1-R3 m97-style 2-barrier structure, two verified deltas:
//  - BK=64: 32 MFMA amortize each barrier pair (vs 16); LDS 32 KB -> 3 blocks/CU.
//    128B row stride would be 16-way bank conflict -> attn-verified chunk^(row&7)
//    XOR swizzle, realized by pre-swizzled global sources (rule #21):
//    LDS[row][c] = global chunk c^(row&7); read chunk (ks*4+quad)^(l16&7).
//  - T1 XCD swizzle: 1-D grid, swz=(bid%8)*(nwg/8)+bid/8 (nwg%8==0, bijective);
//    mt = swz&31, nt = swz>>5 -> 32 co-XCD blocks share one W n-panel.
template <typename OutT>
__global__ __launch_bounds__(256, 3) void gemm_bt64(const bf16* __restrict__ A,
                                                    const bf16* __restrict__ W,
                                                    OutT* __restrict__ Cp,
                                                    int N, int K, int lda) {
  __shared__ __align__(16) bf16 As[128 * 64];
  __shared__ __align__(16) bf16 Ws[128 * 64];
  const int t = threadIdx.x;
  const int w = t >> 6, lane = t & 63;
  const int quad = lane >> 4, l16 = lane & 15;
  const int wr = (w >> 1) * 64, wc = (w & 1) * 64;
  const unsigned bid = blockIdx.x, nwg = gridDim.x;
  const unsigned swz = (bid & 7) * (nwg >> 3) + (bid >> 3);
  const size_t m0 = (size_t)(swz & 31) * 128;
  const size_t n0 = (size_t)(swz >> 5) * 128;

  // staging bases (K-step-invariant): row = is*32 + w*8 + (lane>>3),
  // source chunk pre-swizzled: cg = (lane&7) ^ (lane>>3)
  const int r8 = lane >> 3;
  const int cg = (lane & 7) ^ r8;
  const bf16* aSrc = A + (m0 + w * 8 + r8) * (size_t)lda + cg * 8;
  const bf16* wSrc = W + (n0 + w * 8 + r8) * (size_t)K + cg * 8;
  const size_t sA = (size_t)32 * lda, sW = (size_t)32 * K;

  // per-lane read offsets: chunk = (ks*4+quad)^(l16&7), row base (wr|wc)+l16
  const int cx0 = ((quad) ^ (l16 & 7)) << 4;
  const int cx1 = ((4 + quad) ^ (l16 & 7)) << 4;
  const char* aRb = (const char*)As + (wr + l16) * 128;
  const char* bRb = (const char*)Ws + (wc + l16) * 128;

  f32x4 acc[4][4];
#pragma unroll
  for (int i = 0; i < 4; i++)
#pragma unroll
    for (int j = 0; j < 4; j++) acc[i][j] = f32x4{0.f, 0.f, 0.f, 0.f};

  for (int k0 = 0; k0 < K; k0 += 64) {
    __syncthreads();
#pragma unroll
    for (int is = 0; is < 4; ++is)
      gload16(aSrc + is * sA, (char*)As + is * 4096 + w * 1024);
#pragma unroll
    for (int is = 0; is < 4; ++is)
      gload16(wSrc + is * sW, (char*)Ws + is * 4096 + w * 1024);
    aSrc += 64; wSrc += 64;
    __syncthreads();

    bf16x8 af[4][2], bw[4][2];
#pragma unroll
    for (int i = 0; i < 4; i++) {
      af[i][0] = *(const bf16x8*)(aRb + i * 2048 + cx0);
      af[i][1] = *(const bf16x8*)(aRb + i * 2048 + cx1);
    }
#pragma unroll
    for (int j = 0; j < 4; j++) {
      bw[j][0] = *(const bf16x8*)(bRb + j * 2048 + cx0);
      bw[j][1] = *(const bf16x8*)(bRb + j * 2048 + cx1);
    }
    __builtin_amdgcn_s_setprio(1);
#pragma unroll
    for (int i = 0; i < 4; i++)
#pragma unroll
      for (int j = 0; j < 4; j++)
#pragma unroll
        for (int ks = 0; ks < 2; ks++)
          acc[i][j] = MFMA16x16x32(af[i][ks], bw[j][ks], acc[i][j], 0, 0, 0);
    __builtin_amdgcn_s_setprio(0);
  }

#pragma unroll
  for (int i = 0; i < 4; i++)
#pragma unroll
    for (int j = 0; j < 4; j++)
#pragma unroll
      for (int r = 0; r < 4; r++) {
        size_t row = m0 + wr + i * 16 + quad * 4 + r;
        size_t col = n0 + wc + j * 16 + l16;
        float v = acc[i][j][r];
        if constexpr (std::is_same<OutT, float>::value)
          Cp[row * N + col] = v;
        else
          Cp[row * N + col] = __float2bfloat16(v);
      }
}

// ---------------------------------------------------------------- kv_up GEMM (BK=64) with V-transpose epilogue
// A: (4096,512) stride 2048.  W: (4096,512).  K-halves -> kvraw (4096,4096);
// V-halves -> vT (B,H,128,T).  N-tile of 128 = exactly one half of one head.
// R10 fix: V-half in-head index is wc + j*16 + l16 (NO -128; the half-select
// is already done by n0&128 — the R9 "-128" was a porting bug from the
// 256-wide variant and scribbled d<0).
__global__ __launch_bounds__(256, 3) void gemm_kvup64(const bf16* __restrict__ A,
                                                      const bf16* __restrict__ W,
                                                      bf16* __restrict__ kvraw,
                                                      bf16* __restrict__ vT) {
  __shared__ __align__(16) bf16 As[128 * 64];
  __shared__ __align__(16) bf16 Ws[128 * 64];
  const int t = threadIdx.x;
  const int w = t >> 6, lane = t & 63;
  const int quad = lane >> 4, l16 = lane & 15;
  const int wr = (w >> 1) * 64, wc = (w & 1) * 64;
  const int K = 512, lda = 2048;
  const unsigned bid = blockIdx.x, nwg = gridDim.x;  // nwg = 1024
  const unsigned swz = (bid & 7) * (nwg >> 3) + (bid >> 3);
  const size_t m0 = (size_t)(swz & 31) * 128;
  const int n0 = (int)(swz >> 5) * 128;

  const int r8 = lane >> 3;
  const int cg = (lane & 7) ^ r8;
  const bf16* aSrc = A + (m0 + w * 8 + r8) * (size_t)lda + cg * 8;
  const bf16* wSrc = W + ((size_t)n0 + w * 8 + r8) * (size_t)K + cg * 8;
  const size_t sA = (size_t)32 * lda, sW = (size_t)32 * K;

  const int cx0 = ((quad) ^ (l16 & 7)) << 4;
  const int cx1 = ((4 + quad) ^ (l16 & 7)) << 4;
  const char* aRb = (const char*)As + (wr + l16) * 128;
  const char* bRb = (const char*)Ws + (wc + l16) * 128;

  f32x4 acc[4][4];
#pragma unroll
  for (int i = 0; i < 4; i++)
#pragma unroll
    for (int j = 0; j < 4; j++) acc[i][j] = f32x4{0.f, 0.f, 0.f, 0.f};

  for (int k0 = 0; k0 < K; k0 += 64) {
    __syncthreads();
#pragma unroll
    for (int is = 0; is < 4; ++is)
      gload16(aSrc + is * sA, (char*)As + is * 4096 + w * 1024);
#pragma unroll
    for (int is = 0; is < 4; ++is)
      gload16(wSrc + is * sW, (char*)Ws + is * 4096 + w * 1024);
    aSrc += 64; wSrc += 64;
    __syncthreads();

    bf16x8 af[4][2], bw[4][2];
#pragma unroll
    for (int i = 0; i < 4; i++) {
      af[i][0] = *(const bf16x8*)(aRb + i * 2048 + cx0);
      af[i][1] = *(const bf16x8*)(aRb + i * 2048 + cx1);
    }
#pragma unroll
    for (int j = 0; j < 4; j++) {
      bw[j][0] = *(const bf16x8*)(bRb + j * 2048 + cx0);
      bw[j][1] = *(const bf16x8*)(bRb + j * 2048 + cx1);
    }
    __builtin_amdgcn_s_setprio(1);
#pragma unroll
    for (int i = 0; i < 4; i++)
#pragma unroll
      for (int j = 0; j < 4; j++)
#pragma unroll
        for (int ks = 0; ks < 2; ks++)
          acc[i][j] = MFMA16x16x32(af[i][ks], bw[j][ks], acc[i][j], 0, 0, 0);
    __builtin_amdgcn_s_setprio(0);
  }

  if ((n0 & 128) == 0) {
    // K-half of a head: normal row-major store into kvraw
#pragma unroll
    for (int i = 0; i < 4; i++)
#pragma unroll
      for (int j = 0; j < 4; j++)
#pragma unroll
        for (int r = 0; r < 4; r++) {
          size_t row = m0 + wr + i * 16 + quad * 4 + r;
          size_t col = (size_t)n0 + wc + j * 16 + l16;
          kvraw[row * 4096 + col] = __float2bfloat16(acc[i][j][r]);
        }
  } else {
    // V-half: write transposed into vT[(b*16+h)*128 + d][t], 4 t-contiguous per store
    const int h = n0 >> 8;
#pragma unroll
    for (int i = 0; i < 4; i++) {
      size_t row = m0 + wr + i * 16 + quad * 4;  // +r, all same b
      int bb = (int)(row >> 11), tloc = (int)(row & 2047);
#pragma unroll
      for (int j = 0; j < 4; j++) {
        int d = wc + j * 16 + l16;  // in-head V index, 0..127
        ushort4 v4;
        v4.x = bfbits(acc[i][j][0]);
        v4.y = bfbits(acc[i][j][1]);
        v4.z = bfbits(acc[i][j][2]);
        v4.w = bfbits(acc[i][j][3]);
        *(ushort4*)(vT + ((size_t)(bb * 16 + h) * 128 + d) * 2048 + tloc) = v4;
      }
    }
  }
}

// ---------------------------------------------------------------- RoPE + RMSNorm
__global__ __launch_bounds__(256) void rope_rms(const bf16* __restrict__ qraw,
                                                const bf16* __restrict__ kvraw,
                                                const float* __restrict__ cosp,
                                                const float* __restrict__ sinp,
                                                bf16* __restrict__ qn,
                                                bf16* __restrict__ kn) {
  const int bt = blockIdx.x;
  const int w = threadIdx.x >> 6, lane = threadIdx.x & 63;
  const int h = blockIdx.y * 4 + w;
  const int tt = bt & 2047;  // T = 2048
  const float c = cosp[tt * 32 + (lane & 31)];
  const float s = sinp[tt * 32 + (lane & 31)];
  const float inv128 = 1.0f / 128.0f;
  const float eps = 1.1920929e-7f;

  // Q
  {
    const bf16* base = qraw + (size_t)bt * 2048 + h * 128;
    float a = (float)base[lane];
    float o = (float)base[64 + lane];
    float partner = __shfl_xor(o, 32);
    float orope = (lane < 32) ? (o * c + partner * s) : (o * c - partner * s);
    float ss = a * a + orope * orope;
#pragma unroll
    for (int off = 1; off < 64; off <<= 1) ss += __shfl_xor(ss, off);
    float rn = rsqrtf(ss * inv128 + eps);
    bf16* outp = qn + ((size_t)bt * 16 + h) * 128;
    outp[lane] = __float2bfloat16(a * rn);
    outp[64 + lane] = __float2bfloat16(orope * rn);
  }
  // K
  {
    const bf16* base = kvraw + (size_t)bt * 4096 + h * 256;
    float a = (float)base[lane];
    float o = (float)base[64 + lane];
    float partner = __shfl_xor(o, 32);
    float orope = (lane < 32) ? (o * c + partner * s) : (o * c - partner * s);
    float ss = a * a + orope * orope;
#pragma unroll
    for (int off = 1; off < 64; off <<= 1) ss += __shfl_xor(ss, off);
    float rn = rsqrtf(ss * inv128 + eps);
    bf16* outp = kn + ((size_t)bt * 16 + h) * 128;
    outp[lane] = __float2bfloat16(a * rn);
    outp[64 + lane] = __float2bfloat16(orope * rn);
  }
}

// ---------------------------------------------------------------- flash attention
// R3 version (best verified: 74.7-75.2 us across 3 runs): double-buffer K/V,
// prefetch + vmcnt(8), uniform pairing {31-pr, pr} = 33 tiles/block, KV loop
// unrolled x2 with compile-time buffer index, hoisted bases, setprio on MFMA.
__global__ __launch_bounds__(256, 2) void attn_kernel(const bf16* __restrict__ qn,
                                                      const bf16* __restrict__ kn,
                                                      const bf16* __restrict__ vT,
                                                      bf16* __restrict__ y) {
  __shared__ __align__(16) bf16 Ks[2 * 64 * 128];   // [buf][s][d-chunks swizzled] 32 KB
  __shared__ __align__(16) bf16 Vs[2 * 128 * 64];   // [buf][d][s-chunks swizzled] 32 KB
  __shared__ __align__(16) bf16 Ps[4 * 16 * 64];    // per-wave P, swizzled         8 KB
  const int t = threadIdx.x, w = t >> 6, lane = t & 63;
  const int quad = lane >> 4, l16 = lane & 15;
  const int b = blockIdx.x >> 4, h = blockIdx.x & 15;
  const int pr = (int)blockIdx.y;  // 0..15
  const int T_ = 2048, H_ = 16;
  // p = exp2(sacc * K1 + K2) = e^(sacc/sqrt(128) - 12);  |q.k|/sqrt(128) <= sqrt(128) < 12
  const float K1 = 0.08838834764831845f * 1.4426950408889634f;
  const float K2 = -12.0f * 1.4426950408889634f;

  // per-lane tile-invariant staging bases
  const int cgk = l16 ^ ((w * 4 + quad) & 7);
  const char* kg0 = (const char*)(kn + ((size_t)(b * T_) * H_ + h) * 128)
                    + (size_t)(w * 4 + quad) * 4096 + (size_t)cgk * 16;
  const int vrow = w * 8 + (lane >> 3);
  const int cgv = (lane & 7) ^ (vrow & 7);
  const char* vg0 = (const char*)(vT + ((size_t)(b * H_ + h) * 128 + vrow) * T_)
                    + (size_t)cgv * 16;

  // stage K/V tile it2 into LDS buffer BUF (compile-time)
  auto stage = [&](auto bufc, int it2) {
    constexpr int BUF = decltype(bufc)::value;
    const size_t koff = (size_t)it2 * 262144;  // 64 rows * 4096 B
    const size_t voff = (size_t)it2 * 128;     // 64 cols * 2 B
#pragma unroll
    for (int is = 0; is < 4; ++is)
      gload16(kg0 + koff + (size_t)is * 65536,
              (char*)Ks + BUF * 16384 + is * 4096 + w * 1024);
#pragma unroll
    for (int is = 0; is < 4; ++is)
      gload16(vg0 + voff + (size_t)is * 131072,
              (char*)Vs + BUF * 16384 + is * 4096 + w * 1024);
  };

  // one KV tile: prefetch next into 1-BUF, sync, QK^T, softmax, P->LDS, PV
  auto body = [&](auto bufc, int it, int nt, int xb,
                  bf16x8* qf, f32x4* yacc, float* lrow) {
    constexpr int BUF = decltype(bufc)::value;
    if (it + 1 < nt) {
      stage(std::integral_constant<int, 1 - BUF>{}, it + 1);
      __asm__ volatile("s_waitcnt vmcnt(8)" ::: "memory");  // tile-it loads done
    } else {
      __asm__ volatile("s_waitcnt vmcnt(0)" ::: "memory");
    }
    __asm__ volatile("s_barrier" ::: "memory");

    // S = Q K^T   (kf addr: BUF/cg in offset-immediate, one vaddr per ks)
    f32x4 sacc[4];
#pragma unroll
    for (int cg = 0; cg < 4; cg++) sacc[cg] = f32x4{0.f, 0.f, 0.f, 0.f};
    __builtin_amdgcn_s_setprio(1);
#pragma unroll
    for (int cg = 0; cg < 4; ++cg) {
#pragma unroll
      for (int ks = 0; ks < 4; ++ks) {
        const int pos = (ks * 4 + quad) ^ (l16 & 7);  // srow&7 == l16&7
        const bf16x8 kf = *(const bf16x8*)((const char*)Ks + BUF * 16384 +
                                           (cg * 16 + l16) * 256 + pos * 16);
        sacc[cg] = MFMA16x16x32(qf[ks], kf, sacc[cg], 0, 0, 0);
      }
    }
    __builtin_amdgcn_s_setprio(0);

    // fixed-max softmax: p = exp2(s*K1 + K2); per-lane partial l
    const bool diag = (it == xb);
    float p[4][4];
#pragma unroll
    for (int cg = 0; cg < 4; ++cg)
#pragma unroll
      for (int r = 0; r < 4; ++r) {
        float e;
        if (diag && (cg * 16 + l16 > w * 16 + quad * 4 + r))
          e = 0.0f;
        else
          e = exp2f(fmaf(sacc[cg][r], K1, K2));
        p[cg][r] = e;
        lrow[r] += e;
      }

    // P: C-layout -> LDS (stride 64, chunk-XOR swizzle) -> A-layout
#pragma unroll
    for (int cg = 0; cg < 4; cg++)
#pragma unroll
      for (int r = 0; r < 4; r++) {
        const int row = quad * 4 + r;
        const int col = cg * 16 + l16;
        Ps[w * 1024 + row * 64 + (((col >> 3) ^ (row & 7)) << 3) + (col & 7)] =
            __float2bfloat16(p[cg][r]);
      }
    __asm__ volatile("s_waitcnt lgkmcnt(0)" ::: "memory");

    bf16x8 pf[2];
#pragma unroll
    for (int k2 = 0; k2 < 2; k2++)
      pf[k2] = *(const bf16x8*)(&Ps[w * 1024 + l16 * 64 +
                                    (((k2 * 4 + quad) ^ (l16 & 7)) << 3)]);
    __builtin_amdgcn_s_setprio(1);
#pragma unroll
    for (int dg = 0; dg < 8; dg++) {
#pragma unroll
      for (int k2 = 0; k2 < 2; k2++) {
        const int pos = (k2 * 4 + quad) ^ (l16 & 7);  // drow&7 == l16&7
        const bf16x8 vf = *(const bf16x8*)((const char*)Vs + BUF * 16384 +
                                           (dg * 16 + l16) * 128 + pos * 16);
        yacc[dg] = MFMA16x16x32(pf[k2], vf, yacc[dg], 0, 0, 0);
      }
    }
    __builtin_amdgcn_s_setprio(0);
    __asm__ volatile("s_barrier" ::: "memory");  // 1-BUF free to overwrite
  };

  const std::integral_constant<int, 0> c0{};
  const std::integral_constant<int, 1> c1{};

  for (int sidx = 0; sidx < 2; ++sidx) {
    const int xb = sidx ? pr : (31 - pr);  // long strip first, then short
    const int q0 = xb * 64;
    const int nt = xb + 1;

    bf16x8 qf[4];
    {
      const bf16* qbase = qn + ((size_t)(b * T_ + q0 + w * 16 + l16) * H_ + h) * 128;
#pragma unroll
      for (int ks = 0; ks < 4; ks++) qf[ks] = *(const bf16x8*)(qbase + ks * 32 + quad * 8);
    }
    f32x4 yacc[8];
#pragma unroll
    for (int i = 0; i < 8; i++) yacc[i] = f32x4{0.f, 0.f, 0.f, 0.f};
    float lrow[4] = {0.f, 0.f, 0.f, 0.f};

    stage(c0, 0);  // prologue prefetch into buf0
    int it = 0;
    for (; it + 2 <= nt; it += 2) {
      body(c0, it, nt, xb, qf, yacc, lrow);
      body(c1, it + 1, nt, xb, qf, yacc, lrow);
    }
    if (it < nt) body(c0, it, nt, xb, qf, yacc, lrow);  // odd tail uses buf0

    // epilogue: reduce per-lane l partials across the 16 cols once, then scale
#pragma unroll
    for (int off = 1; off < 16; off <<= 1)
#pragma unroll
      for (int r = 0; r < 4; r++) lrow[r] += __shfl_xor(lrow[r], off);
#pragma unroll
    for (int r = 0; r < 4; r++) {
      float inv = 1.0f / lrow[r];
      size_t qrow = (size_t)(b * T_ + q0 + w * 16 + quad * 4 + r);
      bf16* outp = y + qrow * 2048 + h * 128;
#pragma unroll
      for (int dg = 0; dg < 8; dg++)
        outp[dg * 16 + l16] = __float2bfloat16(yacc[dg][r] * inv);
    }
  }
}

// ---------------------------------------------------------------- launcher
extern "C" void kernel_launch(void* const* d_in, const int* in_sizes, int n_in,
                              void* d_out, int out_size, void* d_ws, size_t ws_size,
                              hipStream_t stream) {
  (void)in_sizes; (void)n_in; (void)out_size; (void)ws_size;
  const float* x    = (const float*)d_in[0];
  const float* cosp = (const float*)d_in[1];
  const float* sinp = (const float*)d_in[2];
  const float* wqd  = (const float*)d_in[3];
  const float* wqu  = (const float*)d_in[4];
  const float* wkvd = (const float*)d_in[5];
  const float* wkvu = (const float*)d_in[6];
  const float* wo   = (const float*)d_in[7];
  float* out = (float*)d_out;

  char* ws = (char*)d_ws;
  size_t off = 0;
  auto alloc = [&](size_t elems) { bf16* p = (bf16*)(ws + off); off += elems * 2; return p; };
  bf16* xb      = alloc((size_t)4096 * 2048);
  bf16* wqdB    = alloc((size_t)1536 * 2048);  // wqdB+wkvdB contiguous: fused (2048,2048) W
  bf16* wkvdB   = alloc((size_t)512 * 2048);
  bf16* wquB    = alloc((size_t)2048 * 1536);
  bf16* wkvuB   = alloc((size_t)4096 * 512);
  bf16* woB     = alloc((size_t)2048 * 2048);
  bf16* qkvdown = alloc((size_t)4096 * 2048);  // cols 0..1535 = qdown, 1536..2047 = kvdown
  bf16* qraw    = alloc((size_t)4096 * 2048);
  bf16* kvraw   = alloc((size_t)4096 * 4096);  // only K-halves written/used
  bf16* qnb     = alloc((size_t)4096 * 16 * 128);
  bf16* knb     = alloc((size_t)4096 * 16 * 128);
  bf16* vTb     = alloc((size_t)2 * 16 * 128 * 2048);
  bf16* yb      = alloc((size_t)4096 * 2048);

  // one fused cast launch for all six fp32->bf16 conversions
  CastArgs ca;
  const float* srcs[6] = {x, wqd, wkvd, wqu, wkvu, wo};
  bf16* dsts[6]        = {xb, wqdB, wkvdB, wquB, wkvuB, woB};
  size_t cnts[6] = {(size_t)4096 * 2048, (size_t)1536 * 2048, (size_t)512 * 2048,
                    (size_t)2048 * 1536, (size_t)4096 * 512,  (size_t)2048 * 2048};
  unsigned cum = 0;
  for (int i = 0; i < 6; i++) {
    ca.src[i] = (const float4*)srcs[i];
    ca.dst[i] = (ushort4*)dsts[i];
    cum += (unsigned)(cnts[i] / 4);
    ca.bound[i] = cum;
  }
  f2bf_multi<<<dim3((cum + 255) / 256), 256, 0, stream>>>(ca);

  // fused down-proj: (4096 x 2048) = x @ [wq_down; wkv_down]^T
  gemm_bt64<bf16><<<dim3(512), 256, 0, stream>>>(xb, wqdB, qkvdown, 2048, 2048, 2048);
  // q up-projection (strided A)
  gemm_bt64<bf16><<<dim3(512), 256, 0, stream>>>(qkvdown, wquB, qraw, 2048, 1536, 2048);
  // kv up-projection with fused V-transpose epilogue
  gemm_kvup64<<<dim3(1024), 256, 0, stream>>>(qkvdown + 1536, wkvuB, kvraw, vTb);
  rope_rms<<<dim3(4096, 4), 256, 0, stream>>>(qraw, kvraw, cosp, sinp, qnb, knb);
  attn_kernel<<<dim3(32, 16), 256, 0, stream>>>(qnb, knb, vTb, yb);
  gemm_bt64<float><<<dim3(512), 256, 0, stream>>>(yb, woB, out, 2048, 2048, 2048);
}